// Round 1
// baseline (3634.667 us; speedup 1.0000x reference)
//
#include <hip/hip_runtime.h>
#include <math.h>

#define BM 128
#define BN 128
#define BKK 16

// GEMM: Y[m,n] = op( sum_k X[m,k] * W(n,k) + bias[n] )
// WT=true : W is [Nout,K] row-major, W(n,k) = W[n*K+k]   (torch Linear weight)
// WT=false: W is [K,Nout] row-major, W(n,k) = W[k*Nout+n] (plain NN product)
// MODE 0: Y = act(v); MODE 1: Y += v (no act); MODE 2: Y *= sigmoid(v)
// ACT: 0 none, 1 leaky(0.01), 2 relu, 3 tanh
template<bool WT, int MODE, int ACT>
__global__ __launch_bounds__(256)
void gemm_k(const float* __restrict__ X, const float* __restrict__ W,
            const float* __restrict__ bias, float* __restrict__ Y,
            int M, int K, int Nout)
{
    __shared__ float Xs[BKK][BM];
    __shared__ float Ws[BKK][BN];
    const int tid = threadIdx.x;
    const int tx = tid & 15, ty = tid >> 4;
    const int m0 = blockIdx.y * BM;
    const int n0 = blockIdx.x * BN;

    float acc[8][8];
#pragma unroll
    for (int i = 0; i < 8; i++)
#pragma unroll
        for (int j = 0; j < 8; j++) acc[i][j] = 0.f;

    for (int k0 = 0; k0 < K; k0 += BKK) {
        // X tile: 128 rows x 16 k, stored transposed Xs[k][row]
#pragma unroll
        for (int t = 0; t < 2; t++) {
            int v = tid * 2 + t;          // 0..511 float4 slots
            int r = v >> 2;               // row in tile
            int kc = (v & 3) << 2;        // k offset
            int gm = m0 + r;
            float4 f = make_float4(0.f, 0.f, 0.f, 0.f);
            if (gm < M) f = *(const float4*)(X + (size_t)gm * K + k0 + kc);
            Xs[kc + 0][r] = f.x; Xs[kc + 1][r] = f.y;
            Xs[kc + 2][r] = f.z; Xs[kc + 3][r] = f.w;
        }
        if (WT) {
#pragma unroll
            for (int t = 0; t < 2; t++) {
                int v = tid * 2 + t;
                int r = v >> 2;           // n in tile
                int kc = (v & 3) << 2;
                int gn = n0 + r;
                float4 f = make_float4(0.f, 0.f, 0.f, 0.f);
                if (gn < Nout) f = *(const float4*)(W + (size_t)gn * K + k0 + kc);
                Ws[kc + 0][r] = f.x; Ws[kc + 1][r] = f.y;
                Ws[kc + 2][r] = f.z; Ws[kc + 3][r] = f.w;
            }
        } else {
#pragma unroll
            for (int t = 0; t < 2; t++) {
                int v = tid * 2 + t;      // 16 rows x 32 float4
                int kr = v >> 5;
                int nc = (v & 31) << 2;
                int gn = n0 + nc;
                float4 f = make_float4(0.f, 0.f, 0.f, 0.f);
                if (gn < Nout) f = *(const float4*)(W + (size_t)(k0 + kr) * Nout + gn);
                *(float4*)&Ws[kr][nc] = f;
            }
        }
        __syncthreads();
#pragma unroll
        for (int k = 0; k < BKK; k++) {
            float xr[8], wr[8];
            *(float4*)&xr[0] = *(const float4*)&Xs[k][ty * 8];
            *(float4*)&xr[4] = *(const float4*)&Xs[k][ty * 8 + 4];
            *(float4*)&wr[0] = *(const float4*)&Ws[k][tx * 8];
            *(float4*)&wr[4] = *(const float4*)&Ws[k][tx * 8 + 4];
#pragma unroll
            for (int i = 0; i < 8; i++)
#pragma unroll
                for (int j = 0; j < 8; j++)
                    acc[i][j] = fmaf(xr[i], wr[j], acc[i][j]);
        }
        __syncthreads();
    }

#pragma unroll
    for (int i = 0; i < 8; i++) {
        int m = m0 + ty * 8 + i;
        if (m < M) {
#pragma unroll
            for (int j = 0; j < 8; j++) {
                int n = n0 + tx * 8 + j;
                if (n < Nout) {
                    float v = acc[i][j] + (bias ? bias[n] : 0.f);
                    size_t idx = (size_t)m * Nout + n;
                    if (MODE == 0) {
                        if (ACT == 1) v = v > 0.f ? v : 0.01f * v;
                        else if (ACT == 2) v = fmaxf(v, 0.f);
                        else if (ACT == 3) v = tanhf(v);
                        Y[idx] = v;
                    } else if (MODE == 1) {
                        Y[idx] += v;
                    } else {
                        Y[idx] *= 1.f / (1.f + expf(-v));
                    }
                }
            }
        }
    }
}

// sum of squares per row of a [M,512] matrix; one wave per row
__global__ __launch_bounds__(256)
void rowsq_k(const float* __restrict__ X, float* __restrict__ out, int M)
{
    int wid = threadIdx.x >> 6, lane = threadIdx.x & 63;
    int row = blockIdx.x * 4 + wid;
    if (row >= M) return;
    const float* xr = X + (size_t)row * 512;
    float s = 0.f;
#pragma unroll
    for (int t = 0; t < 2; t++) {
        float4 a = *(const float4*)(xr + t * 256 + lane * 4);
        s += a.x * a.x + a.y * a.y + a.z * a.z + a.w * a.w;
    }
#pragma unroll
    for (int o = 32; o; o >>= 1) s += __shfl_xor(s, o);
    if (lane == 0) out[row] = s;
}

// in-place row softmax of sim = -sqrt(max(pp+cc-2S,1e-12))/denom over K cols
__global__ __launch_bounds__(256)
void soft_k(float* __restrict__ S, const float* __restrict__ Psq,
            const float* __restrict__ Csq, const float* __restrict__ sim_scale,
            int M, int K)
{
    int wid = threadIdx.x >> 6, lane = threadIdx.x & 63;
    int row = blockIdx.x * 4 + wid;
    if (row >= M) return;
    float denom = fmaxf(1e-6f, sim_scale[0]);
    float pp = Psq[row];
    float* sr = S + (size_t)row * K;
    float v0 = -INFINITY, v1 = -INFINITY;
    if (lane < K)      v0 = -sqrtf(fmaxf(pp + Csq[lane]      - 2.f * sr[lane],      1e-12f)) / denom;
    if (lane + 64 < K) v1 = -sqrtf(fmaxf(pp + Csq[lane + 64] - 2.f * sr[lane + 64], 1e-12f)) / denom;
    float mx = fmaxf(v0, v1);
#pragma unroll
    for (int o = 32; o; o >>= 1) mx = fmaxf(mx, __shfl_xor(mx, o));
    float e0 = (lane < K) ? expf(v0 - mx) : 0.f;
    float e1 = (lane + 64 < K) ? expf(v1 - mx) : 0.f;
    float s = e0 + e1;
#pragma unroll
    for (int o = 32; o; o >>= 1) s += __shfl_xor(s, o);
    float inv = 1.f / s;
    if (lane < K)      sr[lane]      = e0 * inv;
    if (lane + 64 < K) sr[lane + 64] = e1 * inv;
}

// Y = LN(X (+R)) * g + b, rows of 512; one wave per row (in-place safe)
__global__ __launch_bounds__(256)
void ln_k(const float* __restrict__ X, const float* __restrict__ R,
          const float* __restrict__ g, const float* __restrict__ b,
          float* __restrict__ Y, int M)
{
    int wid = threadIdx.x >> 6, lane = threadIdx.x & 63;
    int row = blockIdx.x * 4 + wid;
    if (row >= M) return;
    const float* xr = X + (size_t)row * 512;
    float v[8];
    float s = 0.f, ss = 0.f;
#pragma unroll
    for (int t = 0; t < 2; t++) {
        float4 a = *(const float4*)(xr + t * 256 + lane * 4);
        if (R) {
            float4 c = *(const float4*)(R + (size_t)row * 512 + t * 256 + lane * 4);
            a.x += c.x; a.y += c.y; a.z += c.z; a.w += c.w;
        }
        v[4 * t + 0] = a.x; v[4 * t + 1] = a.y; v[4 * t + 2] = a.z; v[4 * t + 3] = a.w;
    }
#pragma unroll
    for (int q = 0; q < 8; q++) { s += v[q]; ss += v[q] * v[q]; }
#pragma unroll
    for (int o = 32; o; o >>= 1) { s += __shfl_xor(s, o); ss += __shfl_xor(ss, o); }
    float mean = s * (1.f / 512.f);
    float var = ss * (1.f / 512.f) - mean * mean;
    float inv = 1.f / sqrtf(var + 1e-5f);
    float* yr = Y + (size_t)row * 512;
#pragma unroll
    for (int t = 0; t < 2; t++) {
        int d0 = t * 256 + lane * 4;
        float4 o4;
        o4.x = (v[4 * t + 0] - mean) * inv * g[d0 + 0] + b[d0 + 0];
        o4.y = (v[4 * t + 1] - mean) * inv * g[d0 + 1] + b[d0 + 1];
        o4.z = (v[4 * t + 2] - mean) * inv * g[d0 + 2] + b[d0 + 2];
        o4.w = (v[4 * t + 3] - mean) * inv * g[d0 + 3] + b[d0 + 3];
        *(float4*)(yr + d0) = o4;
    }
}

// ProtoReducer stage 1: H1[j,d] = relu(sum_k C[k,d]*w1[j,k] + b1[j])
__global__ __launch_bounds__(256)
void red1_k(const float* __restrict__ C, const float* __restrict__ w1,
            const float* __restrict__ b1, float* __restrict__ H1, int Kin)
{
    int d = blockIdx.x * 256 + threadIdx.x;   // 0..511
    int j = blockIdx.y;
    float acc = b1[j];
    for (int k = 0; k < Kin; k++) acc = fmaf(C[(size_t)k * 512 + d], w1[(size_t)j * Kin + k], acc);
    H1[(size_t)j * 512 + d] = fmaxf(acc, 0.f);
}

// ProtoReducer stage 2: Cn[j2,d] = sum_j H1[j,d]*w2[j2,j] + b2[j2]
__global__ __launch_bounds__(256)
void red2_k(const float* __restrict__ H1, const float* __restrict__ w2,
            const float* __restrict__ b2, float* __restrict__ Cn, int Kin, int Kout)
{
    int d = blockIdx.x * 256 + threadIdx.x;
    int j2 = blockIdx.y;
    float acc = b2[j2];
    for (int j = 0; j < Kin; j++) acc = fmaf(H1[(size_t)j * 512 + d], w2[(size_t)j2 * Kin + j], acc);
    Cn[(size_t)j2 * 512 + d] = acc;
}

// scores[i] = dot(TG[i,:], Ws) + bs; one wave per row
__global__ __launch_bounds__(256)
void score_k(const float* __restrict__ TG, const float* __restrict__ Ws,
             const float* __restrict__ bs, float* __restrict__ out, int M)
{
    int wid = threadIdx.x >> 6, lane = threadIdx.x & 63;
    int row = blockIdx.x * 4 + wid;
    if (row >= M) return;
    const float* xr = TG + (size_t)row * 512;
    float d = 0.f;
#pragma unroll
    for (int t = 0; t < 2; t++) {
        float4 a = *(const float4*)(xr + t * 256 + lane * 4);
        float4 w = *(const float4*)(Ws + t * 256 + lane * 4);
        d += a.x * w.x + a.y * w.y + a.z * w.z + a.w * w.w;
    }
#pragma unroll
    for (int o = 32; o; o >>= 1) d += __shfl_xor(d, o);
    if (lane == 0) out[row] = d + bs[0];
}

// single block: global max, then s[i] <- exp(s[i]-max), scal[0] = sum(exp)
__global__ __launch_bounds__(1024)
void pool_k(float* __restrict__ s, float* __restrict__ scal, int M)
{
    __shared__ float sm[16];
    int tid = threadIdx.x, lane = tid & 63, wid = tid >> 6;
    float mx = -INFINITY;
    for (int i = tid; i < M; i += 1024) mx = fmaxf(mx, s[i]);
#pragma unroll
    for (int o = 32; o; o >>= 1) mx = fmaxf(mx, __shfl_xor(mx, o));
    if (lane == 0) sm[wid] = mx;
    __syncthreads();
    if (wid == 0) {
        float v = (lane < 16) ? sm[lane] : -INFINITY;
#pragma unroll
        for (int o = 8; o; o >>= 1) v = fmaxf(v, __shfl_xor(v, o));
        if (lane == 0) sm[0] = v;
    }
    __syncthreads();
    float gmax = sm[0];
    __syncthreads();
    float sum = 0.f;
    for (int i = tid; i < M; i += 1024) {
        float e = expf(s[i] - gmax);
        s[i] = e;
        sum += e;
    }
#pragma unroll
    for (int o = 32; o; o >>= 1) sum += __shfl_xor(sum, o);
    if (lane == 0) sm[wid] = sum;
    __syncthreads();
    if (tid == 0) {
        float t = 0.f;
        for (int w = 0; w < 16; w++) t += sm[w];
        scal[0] = t;
    }
}

// partial bag: PB[chunk,d] = sum_{i in chunk} w[i]*Z[i,d]
__global__ __launch_bounds__(256)
void bagp_k(const float* __restrict__ Z, const float* __restrict__ w,
            float* __restrict__ PB, int M, int cs)
{
    int d = blockIdx.x * 256 + threadIdx.x;   // 0..511
    int chunk = blockIdx.y;
    int i0 = chunk * cs;
    int i1 = min(M, i0 + cs);
    float acc = 0.f;
    for (int i = i0; i < i1; i++) acc = fmaf(w[i], Z[(size_t)i * 512 + d], acc);
    PB[(size_t)chunk * 512 + d] = acc;
}

__global__ __launch_bounds__(256)
void bagf_k(const float* __restrict__ PB, const float* __restrict__ scal,
            float* __restrict__ bag, int nchunk)
{
    int d = blockIdx.x * 256 + threadIdx.x;
    float acc = 0.f;
    for (int c = 0; c < nchunk; c++) acc += PB[(size_t)c * 512 + d];
    bag[d] = acc / scal[0];
}

// h[j] = relu(dot(bag, Wh[j,:]) + bh[j]); one wave per output
__global__ __launch_bounds__(256)
void h_k(const float* __restrict__ bag, const float* __restrict__ Wh,
         const float* __restrict__ bh, float* __restrict__ h)
{
    int wid = threadIdx.x >> 6, lane = threadIdx.x & 63;
    int j = blockIdx.x * 4 + wid;   // 0..511
    const float* wr = Wh + (size_t)j * 512;
    float d = 0.f;
#pragma unroll
    for (int t = 0; t < 2; t++) {
        float4 a = *(const float4*)(wr + t * 256 + lane * 4);
        float4 bv = *(const float4*)(bag + t * 256 + lane * 4);
        d += a.x * bv.x + a.y * bv.y + a.z * bv.z + a.w * bv.w;
    }
#pragma unroll
    for (int o = 32; o; o >>= 1) d += __shfl_xor(d, o);
    if (lane == 0) h[j] = fmaxf(d + bh[j], 0.f);
}

// logits[j] = dot(h, Wc[j,:]) + bc[j]; 2 waves
__global__ __launch_bounds__(128)
void logit_k(const float* __restrict__ h, const float* __restrict__ Wc,
             const float* __restrict__ bc, float* __restrict__ out)
{
    int wid = threadIdx.x >> 6, lane = threadIdx.x & 63;
    const float* wr = Wc + (size_t)wid * 512;
    float d = 0.f;
#pragma unroll
    for (int t = 0; t < 2; t++) {
        float4 a = *(const float4*)(wr + t * 256 + lane * 4);
        float4 hv = *(const float4*)(h + t * 256 + lane * 4);
        d += a.x * hv.x + a.y * hv.y + a.z * hv.z + a.w * hv.w;
    }
#pragma unroll
    for (int o = 32; o; o >>= 1) d += __shfl_xor(d, o);
    if (lane == 0) out[wid] = d + bc[wid];
}

extern "C" void kernel_launch(void* const* d_in, const int* in_sizes, int n_in,
                              void* d_out, int out_size, void* d_ws, size_t ws_size,
                              hipStream_t stream)
{
    const float* data    = (const float*)d_in[0];
    const float* protos  = (const float*)d_in[1];
    const float* W_pp    = (const float*)d_in[2];
    const float* b_pp    = (const float*)d_in[3];
    const float* W_cp    = (const float*)d_in[4];
    const float* b_cp    = (const float*)d_in[5];
    const float* sscale  = (const float*)d_in[6];
    const float* enh_w1  = (const float*)d_in[7];
    const float* enh_b1  = (const float*)d_in[8];
    const float* enh_w2  = (const float*)d_in[9];
    const float* enh_b2  = (const float*)d_in[10];
    const float* ln_g    = (const float*)d_in[11];
    const float* ln_b    = (const float*)d_in[12];
    const float* red_w1[3] = {(const float*)d_in[13], (const float*)d_in[17], (const float*)d_in[21]};
    const float* red_b1[3] = {(const float*)d_in[14], (const float*)d_in[18], (const float*)d_in[22]};
    const float* red_w2[3] = {(const float*)d_in[15], (const float*)d_in[19], (const float*)d_in[23]};
    const float* red_b2[3] = {(const float*)d_in[16], (const float*)d_in[20], (const float*)d_in[24]};
    const float* W_proc  = (const float*)d_in[25];
    const float* b_proc  = (const float*)d_in[26];
    const float* g_an    = (const float*)d_in[27];
    const float* b_an    = (const float*)d_in[28];
    const float* W_t     = (const float*)d_in[29];
    const float* b_t     = (const float*)d_in[30];
    const float* W_g     = (const float*)d_in[31];
    const float* b_g     = (const float*)d_in[32];
    const float* W_s     = (const float*)d_in[33];
    const float* b_s     = (const float*)d_in[34];
    const float* W_h     = (const float*)d_in[35];
    const float* b_h     = (const float*)d_in[36];
    const float* W_c     = (const float*)d_in[37];
    const float* b_c     = (const float*)d_in[38];
    float* out = (float*)d_out;

    constexpr int N = 32768, DIN = 768, D = 512;
    float* ws = (float*)d_ws;
    float* P    = ws; ws += (size_t)N * D;
    float* TMP  = ws; ws += (size_t)(N + 16) * D;
    float* Z    = ws; ws += (size_t)(N + 16) * D;
    float* S    = ws; ws += (size_t)N * 128;
    float* Psq  = ws; ws += N;
    float* Csq  = ws; ws += 128;
    float* Ca   = ws; ws += 128 * D;
    float* Cb   = ws; ws += 128 * D;
    float* H1   = ws; ws += 128 * D;
    float* scr  = ws; ws += (N + 16);
    float* PB   = ws; ws += 64 * D;
    float* bag  = ws; ws += D;
    float* hb   = ws; ws += D;
    float* scal = ws; ws += 8;

    dim3 blk(256);
    auto ggrid = [](int M, int Nout) { return dim3((Nout + BN - 1) / BN, (M + BM - 1) / BM); };

    // P = leaky(data @ W_pp^T + b_pp), C0 = leaky(protos @ W_cp^T + b_cp)
    gemm_k<true, 0, 1><<<ggrid(N, D), blk, 0, stream>>>(data, W_pp, b_pp, P, N, DIN, D);
    gemm_k<true, 0, 1><<<ggrid(128, D), blk, 0, stream>>>(protos, W_cp, b_cp, Ca, 128, DIN, D);

    float* C = Ca;
    float* Cn = Cb;
    int Kin = 128;
    for (int i = 0; i < 3; i++) {
        int Kout = Kin >> 1;
        rowsq_k<<<dim3((N + 3) / 4), blk, 0, stream>>>(P, Psq, N);
        rowsq_k<<<dim3((Kin + 3) / 4), blk, 0, stream>>>(C, Csq, Kin);
        // S = P @ C^T  [N, Kin]
        gemm_k<true, 0, 0><<<ggrid(N, Kin), blk, 0, stream>>>(P, C, nullptr, S, N, D, Kin);
        // A = softmax(-dist/denom) in place
        soft_k<<<dim3((N + 3) / 4), blk, 0, stream>>>(S, Psq, Csq, sscale, N, Kin);
        // ctx = A @ C  [N, D]
        gemm_k<false, 0, 0><<<ggrid(N, D), blk, 0, stream>>>(S, C, nullptr, TMP, N, Kin, D);
        // P = LN(P + ctx)
        ln_k<<<dim3((N + 3) / 4), blk, 0, stream>>>(P, TMP, ln_g + (size_t)i * D, ln_b + (size_t)i * D, P, N);
        // enhancer MLP: P += relu(P@w1^T+b1)@w2^T+b2
        gemm_k<true, 0, 2><<<ggrid(N, D), blk, 0, stream>>>(P, enh_w1 + (size_t)i * D * D, enh_b1 + (size_t)i * D, TMP, N, D, D);
        gemm_k<true, 1, 0><<<ggrid(N, D), blk, 0, stream>>>(TMP, enh_w2 + (size_t)i * D * D, enh_b2 + (size_t)i * D, P, N, D, D);
        // ProtoReducer on C (over K axis)
        red1_k<<<dim3(2, Kin), blk, 0, stream>>>(C, red_w1[i], red_b1[i], H1, Kin);
        red2_k<<<dim3(2, Kout), blk, 0, stream>>>(H1, red_w2[i], red_b2[i], Cn, Kin, Kout);
        float* t = C; C = Cn; Cn = t;
        Kin = Kout;
    }

    // Z = relu(proc([P; C]))
    gemm_k<true, 0, 2><<<ggrid(N, D), blk, 0, stream>>>(P, W_proc, b_proc, Z, N, D, D);
    gemm_k<true, 0, 2><<<ggrid(16, D), blk, 0, stream>>>(C, W_proc, b_proc, Z + (size_t)N * D, 16, D, D);
    ln_k<<<dim3((N + 16 + 3) / 4), blk, 0, stream>>>(Z, nullptr, g_an, b_an, Z, N + 16);

    // TG = tanh(Z@W_t^T+b_t) * sigmoid(Z@W_g^T+b_g)
    gemm_k<true, 0, 3><<<ggrid(N + 16, D), blk, 0, stream>>>(Z, W_t, b_t, TMP, N + 16, D, D);
    gemm_k<true, 2, 0><<<ggrid(N + 16, D), blk, 0, stream>>>(Z, W_g, b_g, TMP, N + 16, D, D);

    // attention pooling
    score_k<<<dim3((N + 16 + 3) / 4), blk, 0, stream>>>(TMP, W_s, b_s, scr, N + 16);
    pool_k<<<dim3(1), dim3(1024), 0, stream>>>(scr, scal, N + 16);
    int cs = (N + 16 + 63) / 64;
    bagp_k<<<dim3(2, 64), blk, 0, stream>>>(Z, scr, PB, N + 16, cs);
    bagf_k<<<dim3(2), blk, 0, stream>>>(PB, scal, bag, 64);

    // classifier head
    h_k<<<dim3(128), blk, 0, stream>>>(bag, W_h, b_h, hb);
    logit_k<<<dim3(1), dim3(128), 0, stream>>>(hb, W_c, b_c, out);
}

// Round 2
// 2054.799 us; speedup vs baseline: 1.7689x; 1.7689x over previous
//
#include <hip/hip_runtime.h>
#include <math.h>

typedef _Float16 f16x8 __attribute__((ext_vector_type(8)));
typedef _Float16 f16x4 __attribute__((ext_vector_type(4)));
typedef float f32x4 __attribute__((ext_vector_type(4)));

#define BM 128
#define BN 128
#define BKK 16

#define TBM 128
#define TBN 128
#define TBK 32
#define LDK 40  // padded LDS row stride in f16 (32 + 8) -> 2-way banks only

// ---------------- fp32 fallback GEMM (small shapes) ----------------
// WT=true: W is [Nout,K] row-major. MODE 0: Y=act(v). ACT: 0 none,1 leaky,2 relu
template<bool WT, int MODE, int ACT>
__global__ __launch_bounds__(256)
void gemm_k(const float* __restrict__ X, const float* __restrict__ W,
            const float* __restrict__ bias, float* __restrict__ Y,
            int M, int K, int Nout)
{
    __shared__ float Xs[BKK][BM];
    __shared__ float Ws[BKK][BN];
    const int tid = threadIdx.x;
    const int tx = tid & 15, ty = tid >> 4;
    const int m0 = blockIdx.y * BM;
    const int n0 = blockIdx.x * BN;

    float acc[8][8];
#pragma unroll
    for (int i = 0; i < 8; i++)
#pragma unroll
        for (int j = 0; j < 8; j++) acc[i][j] = 0.f;

    for (int k0 = 0; k0 < K; k0 += BKK) {
#pragma unroll
        for (int t = 0; t < 2; t++) {
            int v = tid * 2 + t;
            int r = v >> 2;
            int kc = (v & 3) << 2;
            int gm = m0 + r;
            float4 f = make_float4(0.f, 0.f, 0.f, 0.f);
            if (gm < M) f = *(const float4*)(X + (size_t)gm * K + k0 + kc);
            Xs[kc + 0][r] = f.x; Xs[kc + 1][r] = f.y;
            Xs[kc + 2][r] = f.z; Xs[kc + 3][r] = f.w;
        }
#pragma unroll
        for (int t = 0; t < 2; t++) {
            int v = tid * 2 + t;
            int r = v >> 2;
            int kc = (v & 3) << 2;
            int gn = n0 + r;
            float4 f = make_float4(0.f, 0.f, 0.f, 0.f);
            if (gn < Nout) f = *(const float4*)(W + (size_t)gn * K + k0 + kc);
            Ws[kc + 0][r] = f.x; Ws[kc + 1][r] = f.y;
            Ws[kc + 2][r] = f.z; Ws[kc + 3][r] = f.w;
        }
        __syncthreads();
#pragma unroll
        for (int k = 0; k < BKK; k++) {
            float xr[8], wr[8];
            *(float4*)&xr[0] = *(const float4*)&Xs[k][ty * 8];
            *(float4*)&xr[4] = *(const float4*)&Xs[k][ty * 8 + 4];
            *(float4*)&wr[0] = *(const float4*)&Ws[k][tx * 8];
            *(float4*)&wr[4] = *(const float4*)&Ws[k][tx * 8 + 4];
#pragma unroll
            for (int i = 0; i < 8; i++)
#pragma unroll
                for (int j = 0; j < 8; j++)
                    acc[i][j] = fmaf(xr[i], wr[j], acc[i][j]);
        }
        __syncthreads();
    }

#pragma unroll
    for (int i = 0; i < 8; i++) {
        int m = m0 + ty * 8 + i;
        if (m < M) {
#pragma unroll
            for (int j = 0; j < 8; j++) {
                int n = n0 + tx * 8 + j;
                if (n < Nout) {
                    float v = acc[i][j] + (bias ? bias[n] : 0.f);
                    size_t idx = (size_t)m * Nout + n;
                    if (ACT == 1) v = v > 0.f ? v : 0.01f * v;
                    else if (ACT == 2) v = fmaxf(v, 0.f);
                    Y[idx] = v;
                }
            }
        }
    }
}

// ---------------- f16 MFMA GEMM ----------------
// Y[m,n] = op( sum_k A[m,k]*B[n,k] + bias[n] )
// A [M,K] f16 row-major, B [Nout,K] f16 row-major (torch Linear layout)
// MODE 0: Y = act(v); 1: Y += v; 2: Y *= sigmoid(v)
// ACT: 0 none, 1 leaky, 2 relu, 3 tanh
// OUT: 0 fp32 only, 1 fp32 + f16 shadow, 2 f16 only (MODE 0 only)
template<int MODE, int ACT, int OUT>
__global__ __launch_bounds__(256)
void mgemm(const _Float16* __restrict__ A, const _Float16* __restrict__ B,
           const float* __restrict__ bias, float* __restrict__ Y,
           _Float16* __restrict__ Yh, int M, int K, int Nout)
{
    __shared__ _Float16 As[TBM * LDK];
    __shared__ _Float16 Bs[TBM * LDK];
    const int tid = threadIdx.x;
    const int lane = tid & 63;
    const int wid = tid >> 6;
    const int wr = wid >> 1, wc = wid & 1;
    const int m0 = blockIdx.y * TBM;
    const int n0 = blockIdx.x * TBN;

    const int srow = tid >> 2;           // 0..63
    const int skoff = (tid & 3) * 8;     // f16 elems (16B granules)

    f32x4 acc[4][4] = {};

    const int nt = K / TBK;
    float4 ra[2], rb[2];
    {
        const int k0 = 0;
#pragma unroll
        for (int p = 0; p < 2; p++) {
            int row = p * 64 + srow;
            int am = min(m0 + row, M - 1);
            int bn = min(n0 + row, Nout - 1);
            ra[p] = *(const float4*)(A + (size_t)am * K + k0 + skoff);
            rb[p] = *(const float4*)(B + (size_t)bn * K + k0 + skoff);
        }
    }
    for (int t = 0; t < nt; ++t) {
#pragma unroll
        for (int p = 0; p < 2; p++) {
            int row = p * 64 + srow;
            *(float4*)(As + row * LDK + skoff) = ra[p];
            *(float4*)(Bs + row * LDK + skoff) = rb[p];
        }
        __syncthreads();
        if (t + 1 < nt) {
            const int k0 = (t + 1) * TBK;
#pragma unroll
            for (int p = 0; p < 2; p++) {
                int row = p * 64 + srow;
                int am = min(m0 + row, M - 1);
                int bn = min(n0 + row, Nout - 1);
                ra[p] = *(const float4*)(A + (size_t)am * K + k0 + skoff);
                rb[p] = *(const float4*)(B + (size_t)bn * K + k0 + skoff);
            }
        }
        f16x8 af[4], bf[4];
#pragma unroll
        for (int mi = 0; mi < 4; mi++)
            af[mi] = *(const f16x8*)(As + (wr * 64 + mi * 16 + (lane & 15)) * LDK + (lane >> 4) * 8);
#pragma unroll
        for (int nj = 0; nj < 4; nj++)
            bf[nj] = *(const f16x8*)(Bs + (wc * 64 + nj * 16 + (lane & 15)) * LDK + (lane >> 4) * 8);
#pragma unroll
        for (int mi = 0; mi < 4; mi++)
#pragma unroll
            for (int nj = 0; nj < 4; nj++)
                acc[mi][nj] = __builtin_amdgcn_mfma_f32_16x16x32_f16(af[mi], bf[nj], acc[mi][nj], 0, 0, 0);
        __syncthreads();
    }

#pragma unroll
    for (int mi = 0; mi < 4; mi++) {
        int mbase = m0 + wr * 64 + mi * 16 + (lane >> 4) * 4;
#pragma unroll
        for (int nj = 0; nj < 4; nj++) {
            int n = n0 + wc * 64 + nj * 16 + (lane & 15);
            if (n < Nout) {
                float bv = bias ? bias[n] : 0.f;
#pragma unroll
                for (int r = 0; r < 4; r++) {
                    int m = mbase + r;
                    if (m < M) {
                        float v = acc[mi][nj][r] + bv;
                        size_t idx = (size_t)m * Nout + n;
                        if (MODE == 0) {
                            if (ACT == 1) v = v > 0.f ? v : 0.01f * v;
                            else if (ACT == 2) v = fmaxf(v, 0.f);
                            else if (ACT == 3) v = tanhf(v);
                            if (OUT != 2) Y[idx] = v;
                            if (OUT != 0) Yh[idx] = (_Float16)v;
                        } else if (MODE == 1) {
                            float s = Y[idx] + v;
                            Y[idx] = s;
                            if (OUT != 0) Yh[idx] = (_Float16)s;
                        } else {
                            float s = Y[idx] * (1.f / (1.f + expf(-v)));
                            Y[idx] = s;
                            if (OUT != 0) Yh[idx] = (_Float16)s;
                        }
                    }
                }
            }
        }
    }
}

// ---------------- converters ----------------
__global__ __launch_bounds__(256)
void cvt_k(const float* __restrict__ x, _Float16* __restrict__ y, int n)
{
    int i = (blockIdx.x * 256 + threadIdx.x) * 4;
    if (i < n) {
        float4 v = *(const float4*)(x + i);
        f16x4 h = { (_Float16)v.x, (_Float16)v.y, (_Float16)v.z, (_Float16)v.w };
        *(f16x4*)(y + i) = h;
    }
}

// C [Kin,512] fp32 -> Ch [Kin,512] f16 and CTh [512,Kin] f16
__global__ __launch_bounds__(256)
void cvtC_k(const float* __restrict__ C, _Float16* __restrict__ Ch,
            _Float16* __restrict__ CTh, int Kin)
{
    int i = blockIdx.x * 256 + threadIdx.x;
    if (i < Kin * 512) {
        int j = i >> 9, d = i & 511;
        float v = C[i];
        Ch[i] = (_Float16)v;
        CTh[d * Kin + j] = (_Float16)v;
    }
}

// ---------------- small kernels ----------------
__global__ __launch_bounds__(256)
void rowsq_k(const float* __restrict__ X, float* __restrict__ out, int M)
{
    int wid = threadIdx.x >> 6, lane = threadIdx.x & 63;
    int row = blockIdx.x * 4 + wid;
    if (row >= M) return;
    const float* xr = X + (size_t)row * 512;
    float s = 0.f;
#pragma unroll
    for (int t = 0; t < 2; t++) {
        float4 a = *(const float4*)(xr + t * 256 + lane * 4);
        s += a.x * a.x + a.y * a.y + a.z * a.z + a.w * a.w;
    }
#pragma unroll
    for (int o = 32; o; o >>= 1) s += __shfl_xor(s, o);
    if (lane == 0) out[row] = s;
}

// softmax over K cols of -sqrt(max(pp+cc-2S,1e-12))/denom ; writes f16 A
__global__ __launch_bounds__(256)
void soft_k(const float* __restrict__ S, const float* __restrict__ Psq,
            const float* __restrict__ Csq, const float* __restrict__ sim_scale,
            _Float16* __restrict__ Ah, int M, int K)
{
    int wid = threadIdx.x >> 6, lane = threadIdx.x & 63;
    int row = blockIdx.x * 4 + wid;
    if (row >= M) return;
    float denom = fmaxf(1e-6f, sim_scale[0]);
    float pp = Psq[row];
    const float* sr = S + (size_t)row * K;
    float v0 = -INFINITY, v1 = -INFINITY;
    if (lane < K)      v0 = -sqrtf(fmaxf(pp + Csq[lane]      - 2.f * sr[lane],      1e-12f)) / denom;
    if (lane + 64 < K) v1 = -sqrtf(fmaxf(pp + Csq[lane + 64] - 2.f * sr[lane + 64], 1e-12f)) / denom;
    float mx = fmaxf(v0, v1);
#pragma unroll
    for (int o = 32; o; o >>= 1) mx = fmaxf(mx, __shfl_xor(mx, o));
    float e0 = (lane < K) ? expf(v0 - mx) : 0.f;
    float e1 = (lane + 64 < K) ? expf(v1 - mx) : 0.f;
    float s = e0 + e1;
#pragma unroll
    for (int o = 32; o; o >>= 1) s += __shfl_xor(s, o);
    float inv = 1.f / s;
    _Float16* ar = Ah + (size_t)row * K;
    if (lane < K)      ar[lane]      = (_Float16)(e0 * inv);
    if (lane + 64 < K) ar[lane + 64] = (_Float16)(e1 * inv);
}

// Y = LN(X (+R)) * g + b ; optional f16 shadow
__global__ __launch_bounds__(256)
void ln_k(const float* __restrict__ X, const float* __restrict__ R,
          const float* __restrict__ g, const float* __restrict__ b,
          float* __restrict__ Y, _Float16* __restrict__ Yh, int M)
{
    int wid = threadIdx.x >> 6, lane = threadIdx.x & 63;
    int row = blockIdx.x * 4 + wid;
    if (row >= M) return;
    const float* xr = X + (size_t)row * 512;
    float v[8];
    float s = 0.f, ss = 0.f;
#pragma unroll
    for (int t = 0; t < 2; t++) {
        float4 a = *(const float4*)(xr + t * 256 + lane * 4);
        if (R) {
            float4 c = *(const float4*)(R + (size_t)row * 512 + t * 256 + lane * 4);
            a.x += c.x; a.y += c.y; a.z += c.z; a.w += c.w;
        }
        v[4 * t + 0] = a.x; v[4 * t + 1] = a.y; v[4 * t + 2] = a.z; v[4 * t + 3] = a.w;
    }
#pragma unroll
    for (int q = 0; q < 8; q++) { s += v[q]; ss += v[q] * v[q]; }
#pragma unroll
    for (int o = 32; o; o >>= 1) { s += __shfl_xor(s, o); ss += __shfl_xor(ss, o); }
    float mean = s * (1.f / 512.f);
    float var = ss * (1.f / 512.f) - mean * mean;
    float inv = 1.f / sqrtf(var + 1e-5f);
    float* yr = Y + (size_t)row * 512;
#pragma unroll
    for (int t = 0; t < 2; t++) {
        int d0 = t * 256 + lane * 4;
        float4 o4;
        o4.x = (v[4 * t + 0] - mean) * inv * g[d0 + 0] + b[d0 + 0];
        o4.y = (v[4 * t + 1] - mean) * inv * g[d0 + 1] + b[d0 + 1];
        o4.z = (v[4 * t + 2] - mean) * inv * g[d0 + 2] + b[d0 + 2];
        o4.w = (v[4 * t + 3] - mean) * inv * g[d0 + 3] + b[d0 + 3];
        *(float4*)(yr + d0) = o4;
        if (Yh) {
            f16x4 h = { (_Float16)o4.x, (_Float16)o4.y, (_Float16)o4.z, (_Float16)o4.w };
            *(f16x4*)(Yh + (size_t)row * 512 + d0) = h;
        }
    }
}

__global__ __launch_bounds__(256)
void red1_k(const float* __restrict__ C, const float* __restrict__ w1,
            const float* __restrict__ b1, float* __restrict__ H1, int Kin)
{
    int d = blockIdx.x * 256 + threadIdx.x;
    int j = blockIdx.y;
    float acc = b1[j];
    for (int k = 0; k < Kin; k++) acc = fmaf(C[(size_t)k * 512 + d], w1[(size_t)j * Kin + k], acc);
    H1[(size_t)j * 512 + d] = fmaxf(acc, 0.f);
}

__global__ __launch_bounds__(256)
void red2_k(const float* __restrict__ H1, const float* __restrict__ w2,
            const float* __restrict__ b2, float* __restrict__ Cn, int Kin, int Kout)
{
    int d = blockIdx.x * 256 + threadIdx.x;
    int j2 = blockIdx.y;
    float acc = b2[j2];
    for (int j = 0; j < Kin; j++) acc = fmaf(H1[(size_t)j * 512 + d], w2[(size_t)j2 * Kin + j], acc);
    Cn[(size_t)j2 * 512 + d] = acc;
}

__global__ __launch_bounds__(256)
void score_k(const float* __restrict__ TG, const float* __restrict__ Ws,
             const float* __restrict__ bs, float* __restrict__ out, int M)
{
    int wid = threadIdx.x >> 6, lane = threadIdx.x & 63;
    int row = blockIdx.x * 4 + wid;
    if (row >= M) return;
    const float* xr = TG + (size_t)row * 512;
    float d = 0.f;
#pragma unroll
    for (int t = 0; t < 2; t++) {
        float4 a = *(const float4*)(xr + t * 256 + lane * 4);
        float4 w = *(const float4*)(Ws + t * 256 + lane * 4);
        d += a.x * w.x + a.y * w.y + a.z * w.z + a.w * w.w;
    }
#pragma unroll
    for (int o = 32; o; o >>= 1) d += __shfl_xor(d, o);
    if (lane == 0) out[row] = d + bs[0];
}

__global__ __launch_bounds__(1024)
void pool_k(float* __restrict__ s, float* __restrict__ scal, int M)
{
    __shared__ float sm[16];
    int tid = threadIdx.x, lane = tid & 63, wid = tid >> 6;
    float mx = -INFINITY;
    for (int i = tid; i < M; i += 1024) mx = fmaxf(mx, s[i]);
#pragma unroll
    for (int o = 32; o; o >>= 1) mx = fmaxf(mx, __shfl_xor(mx, o));
    if (lane == 0) sm[wid] = mx;
    __syncthreads();
    if (wid == 0) {
        float v = (lane < 16) ? sm[lane] : -INFINITY;
#pragma unroll
        for (int o = 8; o; o >>= 1) v = fmaxf(v, __shfl_xor(v, o));
        if (lane == 0) sm[0] = v;
    }
    __syncthreads();
    float gmax = sm[0];
    __syncthreads();
    float sum = 0.f;
    for (int i = tid; i < M; i += 1024) {
        float e = expf(s[i] - gmax);
        s[i] = e;
        sum += e;
    }
#pragma unroll
    for (int o = 32; o; o >>= 1) sum += __shfl_xor(sum, o);
    if (lane == 0) sm[wid] = sum;
    __syncthreads();
    if (tid == 0) {
        float t = 0.f;
        for (int w = 0; w < 16; w++) t += sm[w];
        scal[0] = t;
    }
}

__global__ __launch_bounds__(256)
void bagp_k(const float* __restrict__ Z, const float* __restrict__ w,
            float* __restrict__ PB, int M, int cs)
{
    int d = blockIdx.x * 256 + threadIdx.x;
    int chunk = blockIdx.y;
    int i0 = chunk * cs;
    int i1 = min(M, i0 + cs);
    float acc = 0.f;
    for (int i = i0; i < i1; i++) acc = fmaf(w[i], Z[(size_t)i * 512 + d], acc);
    PB[(size_t)chunk * 512 + d] = acc;
}

__global__ __launch_bounds__(256)
void bagf_k(const float* __restrict__ PB, const float* __restrict__ scal,
            float* __restrict__ bag, int nchunk)
{
    int d = blockIdx.x * 256 + threadIdx.x;
    float acc = 0.f;
    for (int c = 0; c < nchunk; c++) acc += PB[(size_t)c * 512 + d];
    bag[d] = acc / scal[0];
}

__global__ __launch_bounds__(256)
void h_k(const float* __restrict__ bag, const float* __restrict__ Wh,
         const float* __restrict__ bh, float* __restrict__ h)
{
    int wid = threadIdx.x >> 6, lane = threadIdx.x & 63;
    int j = blockIdx.x * 4 + wid;
    const float* wr = Wh + (size_t)j * 512;
    float d = 0.f;
#pragma unroll
    for (int t = 0; t < 2; t++) {
        float4 a = *(const float4*)(wr + t * 256 + lane * 4);
        float4 bv = *(const float4*)(bag + t * 256 + lane * 4);
        d += a.x * bv.x + a.y * bv.y + a.z * bv.z + a.w * bv.w;
    }
#pragma unroll
    for (int o = 32; o; o >>= 1) d += __shfl_xor(d, o);
    if (lane == 0) h[j] = fmaxf(d + bh[j], 0.f);
}

__global__ __launch_bounds__(128)
void logit_k(const float* __restrict__ h, const float* __restrict__ Wc,
             const float* __restrict__ bc, float* __restrict__ out)
{
    int wid = threadIdx.x >> 6, lane = threadIdx.x & 63;
    const float* wr = Wc + (size_t)wid * 512;
    float d = 0.f;
#pragma unroll
    for (int t = 0; t < 2; t++) {
        float4 a = *(const float4*)(wr + t * 256 + lane * 4);
        float4 hv = *(const float4*)(h + t * 256 + lane * 4);
        d += a.x * hv.x + a.y * hv.y + a.z * hv.z + a.w * hv.w;
    }
#pragma unroll
    for (int o = 32; o; o >>= 1) d += __shfl_xor(d, o);
    if (lane == 0) out[wid] = d + bc[wid];
}

extern "C" void kernel_launch(void* const* d_in, const int* in_sizes, int n_in,
                              void* d_out, int out_size, void* d_ws, size_t ws_size,
                              hipStream_t stream)
{
    const float* data    = (const float*)d_in[0];
    const float* protos  = (const float*)d_in[1];
    const float* W_pp    = (const float*)d_in[2];
    const float* b_pp    = (const float*)d_in[3];
    const float* W_cp    = (const float*)d_in[4];
    const float* b_cp    = (const float*)d_in[5];
    const float* sscale  = (const float*)d_in[6];
    const float* enh_w1  = (const float*)d_in[7];
    const float* enh_b1  = (const float*)d_in[8];
    const float* enh_w2  = (const float*)d_in[9];
    const float* enh_b2  = (const float*)d_in[10];
    const float* ln_g    = (const float*)d_in[11];
    const float* ln_b    = (const float*)d_in[12];
    const float* red_w1[3] = {(const float*)d_in[13], (const float*)d_in[17], (const float*)d_in[21]};
    const float* red_b1[3] = {(const float*)d_in[14], (const float*)d_in[18], (const float*)d_in[22]};
    const float* red_w2[3] = {(const float*)d_in[15], (const float*)d_in[19], (const float*)d_in[23]};
    const float* red_b2[3] = {(const float*)d_in[16], (const float*)d_in[20], (const float*)d_in[24]};
    const float* W_proc  = (const float*)d_in[25];
    const float* b_proc  = (const float*)d_in[26];
    const float* g_an    = (const float*)d_in[27];
    const float* b_an    = (const float*)d_in[28];
    const float* W_t     = (const float*)d_in[29];
    const float* b_t     = (const float*)d_in[30];
    const float* W_g     = (const float*)d_in[31];
    const float* b_g     = (const float*)d_in[32];
    const float* W_s     = (const float*)d_in[33];
    const float* b_s     = (const float*)d_in[34];
    const float* W_h     = (const float*)d_in[35];
    const float* b_h     = (const float*)d_in[36];
    const float* W_c     = (const float*)d_in[37];
    const float* b_c     = (const float*)d_in[38];
    float* out = (float*)d_out;

    constexpr int N = 32768, DIN = 768, D = 512;
    char* w = (char*)d_ws;
    auto alloc = [&](size_t bytes) -> char* {
        char* p = w; w += (bytes + 255) & ~(size_t)255; return p;
    };
    float*    P      = (float*)alloc((size_t)N * D * 4);
    float*    TMP    = (float*)alloc((size_t)(N + 16) * D * 4);
    float*    Z      = (float*)alloc((size_t)(N + 16) * D * 4);
    _Float16* Ph     = (_Float16*)alloc((size_t)N * D * 2);
    _Float16* Zh     = (_Float16*)alloc((size_t)(N + 16) * D * 2);
    _Float16* Ah     = (_Float16*)alloc((size_t)N * 128 * 2);
    _Float16* Ch     = (_Float16*)alloc(128 * D * 2);
    _Float16* CTh    = (_Float16*)alloc(128 * D * 2);
    _Float16* Wpph   = (_Float16*)alloc((size_t)D * DIN * 2);
    _Float16* w1h    = (_Float16*)alloc((size_t)3 * D * D * 2);
    _Float16* w2h    = (_Float16*)alloc((size_t)3 * D * D * 2);
    _Float16* Wproch = (_Float16*)alloc((size_t)D * D * 2);
    _Float16* Wth    = (_Float16*)alloc((size_t)D * D * 2);
    _Float16* Wgh    = (_Float16*)alloc((size_t)D * D * 2);
    float*    Psq    = (float*)alloc((size_t)N * 4);
    float*    Csq    = (float*)alloc(128 * 4);
    float*    Ca     = (float*)alloc(128 * D * 4);
    float*    Cb     = (float*)alloc(128 * D * 4);
    float*    H1     = (float*)alloc(128 * D * 4);
    float*    scr    = (float*)alloc((size_t)(N + 16) * 4);
    float*    PB     = (float*)alloc(64 * D * 4);
    float*    bag    = (float*)alloc(D * 4);
    float*    hb     = (float*)alloc(D * 4);
    float*    scal   = (float*)alloc(8 * 4);
    // aliases (lifetimes disjoint)
    _Float16* datah  = (_Float16*)Z;      // data f16, dead before Z written
    float*    S      = TMP;               // sim matrix, dead before ctx written
    _Float16* TMPh   = (_Float16*)TMP;    // enh hidden f16, after ctx consumed

    dim3 blk(256);
    auto cgrid = [](size_t n) { return dim3((unsigned)((n / 4 + 255) / 256)); };
    auto mgrid = [](int M_, int Nout_) { return dim3((Nout_ + TBN - 1) / TBN, (M_ + TBM - 1) / TBM); };

    // --- convert weights + data to f16 ---
    cvt_k<<<cgrid((size_t)N * DIN), blk, 0, stream>>>(data, datah, N * DIN);
    cvt_k<<<cgrid((size_t)D * DIN), blk, 0, stream>>>(W_pp, Wpph, D * DIN);
    cvt_k<<<cgrid((size_t)3 * D * D), blk, 0, stream>>>(enh_w1, w1h, 3 * D * D);
    cvt_k<<<cgrid((size_t)3 * D * D), blk, 0, stream>>>(enh_w2, w2h, 3 * D * D);
    cvt_k<<<cgrid((size_t)D * D), blk, 0, stream>>>(W_proc, Wproch, D * D);
    cvt_k<<<cgrid((size_t)D * D), blk, 0, stream>>>(W_t, Wth, D * D);
    cvt_k<<<cgrid((size_t)D * D), blk, 0, stream>>>(W_g, Wgh, D * D);

    // P = leaky(data @ W_pp^T + b_pp)  (fp32 + f16 shadow)
    mgemm<0, 1, 1><<<mgrid(N, D), blk, 0, stream>>>(datah, Wpph, b_pp, P, Ph, N, DIN, D);
    // C0 = leaky(protos @ W_cp^T + b_cp)  (fp32, small)
    gemm_k<true, 0, 1><<<dim3(4, 1), blk, 0, stream>>>(protos, W_cp, b_cp, Ca, 128, DIN, D);

    float* C = Ca;
    float* Cn = Cb;
    int Kin = 128;
    for (int i = 0; i < 3; i++) {
        int Kout = Kin >> 1;
        rowsq_k<<<dim3((N + 3) / 4), blk, 0, stream>>>(P, Psq, N);
        rowsq_k<<<dim3((Kin + 3) / 4), blk, 0, stream>>>(C, Csq, Kin);
        cvtC_k<<<dim3((Kin * D + 255) / 256), blk, 0, stream>>>(C, Ch, CTh, Kin);
        // S = P @ C^T
        mgemm<0, 0, 0><<<mgrid(N, Kin), blk, 0, stream>>>(Ph, Ch, nullptr, S, nullptr, N, D, Kin);
        // A = softmax(-dist/denom) -> f16
        soft_k<<<dim3((N + 3) / 4), blk, 0, stream>>>(S, Psq, Csq, sscale, Ah, N, Kin);
        // ctx = A @ C
        mgemm<0, 0, 0><<<mgrid(N, D), blk, 0, stream>>>(Ah, CTh, nullptr, TMP, nullptr, N, Kin, D);
        // P = LN(P + ctx)
        ln_k<<<dim3((N + 3) / 4), blk, 0, stream>>>(P, TMP, ln_g + (size_t)i * D, ln_b + (size_t)i * D, P, Ph, N);
        // enhancer MLP
        mgemm<0, 2, 2><<<mgrid(N, D), blk, 0, stream>>>(Ph, w1h + (size_t)i * D * D, enh_b1 + (size_t)i * D, nullptr, TMPh, N, D, D);
        mgemm<1, 0, 1><<<mgrid(N, D), blk, 0, stream>>>(TMPh, w2h + (size_t)i * D * D, enh_b2 + (size_t)i * D, P, Ph, N, D, D);
        // ProtoReducer (fp32, tiny)
        red1_k<<<dim3(2, Kin), blk, 0, stream>>>(C, red_w1[i], red_b1[i], H1, Kin);
        red2_k<<<dim3(2, Kout), blk, 0, stream>>>(H1, red_w2[i], red_b2[i], Cn, Kin, Kout);
        float* t = C; C = Cn; Cn = t;
        Kin = Kout;
    }

    // Z = relu(proc([P; C]))
    mgemm<0, 2, 0><<<mgrid(N, D), blk, 0, stream>>>(Ph, Wproch, b_proc, Z, nullptr, N, D, D);
    gemm_k<true, 0, 2><<<dim3(4, 1), blk, 0, stream>>>(C, W_proc, b_proc, Z + (size_t)N * D, 16, D, D);
    ln_k<<<dim3((N + 16 + 3) / 4), blk, 0, stream>>>(Z, nullptr, g_an, b_an, Z, Zh, N + 16);

    // TG = tanh(Z@W_t^T+b_t) * sigmoid(Z@W_g^T+b_g)
    mgemm<0, 3, 0><<<mgrid(N + 16, D), blk, 0, stream>>>(Zh, Wth, b_t, TMP, nullptr, N + 16, D, D);
    mgemm<2, 0, 0><<<mgrid(N + 16, D), blk, 0, stream>>>(Zh, Wgh, b_g, TMP, nullptr, N + 16, D, D);

    // attention pooling
    score_k<<<dim3((N + 16 + 3) / 4), blk, 0, stream>>>(TMP, W_s, b_s, scr, N + 16);
    pool_k<<<dim3(1), dim3(1024), 0, stream>>>(scr, scal, N + 16);
    int cs = (N + 16 + 63) / 64;
    bagp_k<<<dim3(2, 64), blk, 0, stream>>>(Z, scr, PB, N + 16, cs);
    bagf_k<<<dim3(2), blk, 0, stream>>>(PB, scal, bag, 64);

    // classifier head
    h_k<<<dim3(128), blk, 0, stream>>>(bag, W_h, b_h, hb);
    logit_k<<<dim3(1), dim3(128), 0, stream>>>(hb, W_c, b_c, out);
}

// Round 3
// 1495.045 us; speedup vs baseline: 2.4311x; 1.3744x over previous
//
#include <hip/hip_runtime.h>
#include <math.h>

typedef _Float16 f16x8 __attribute__((ext_vector_type(8)));
typedef _Float16 f16x4 __attribute__((ext_vector_type(4)));
typedef float f32x4 __attribute__((ext_vector_type(4)));

#define BM 128
#define BN 128
#define BKK 16

#define TBM 128
#define TBN 128
#define TBK 32

#define AS1 __attribute__((address_space(1)))
#define AS3 __attribute__((address_space(3)))

__device__ __forceinline__ void gll16(const _Float16* g, _Float16* l)
{
    // direct global->LDS, 16B per lane; LDS dest = wave-uniform base + lane*16
    __builtin_amdgcn_global_load_lds((const AS1 unsigned int*)g,
                                     (AS3 unsigned int*)l, 16, 0, 0);
}

// ---------------- fp32 fallback GEMM (small shapes) ----------------
template<bool WT, int MODE, int ACT>
__global__ __launch_bounds__(256)
void gemm_k(const float* __restrict__ X, const float* __restrict__ W,
            const float* __restrict__ bias, float* __restrict__ Y,
            int M, int K, int Nout)
{
    __shared__ float Xs[BKK][BM];
    __shared__ float Ws[BKK][BN];
    const int tid = threadIdx.x;
    const int tx = tid & 15, ty = tid >> 4;
    const int m0 = blockIdx.y * BM;
    const int n0 = blockIdx.x * BN;

    float acc[8][8];
#pragma unroll
    for (int i = 0; i < 8; i++)
#pragma unroll
        for (int j = 0; j < 8; j++) acc[i][j] = 0.f;

    for (int k0 = 0; k0 < K; k0 += BKK) {
#pragma unroll
        for (int t = 0; t < 2; t++) {
            int v = tid * 2 + t;
            int r = v >> 2;
            int kc = (v & 3) << 2;
            int gm = m0 + r;
            float4 f = make_float4(0.f, 0.f, 0.f, 0.f);
            if (gm < M) f = *(const float4*)(X + (size_t)gm * K + k0 + kc);
            Xs[kc + 0][r] = f.x; Xs[kc + 1][r] = f.y;
            Xs[kc + 2][r] = f.z; Xs[kc + 3][r] = f.w;
        }
#pragma unroll
        for (int t = 0; t < 2; t++) {
            int v = tid * 2 + t;
            int r = v >> 2;
            int kc = (v & 3) << 2;
            int gn = n0 + r;
            float4 f = make_float4(0.f, 0.f, 0.f, 0.f);
            if (gn < Nout) f = *(const float4*)(W + (size_t)gn * K + k0 + kc);
            Ws[kc + 0][r] = f.x; Ws[kc + 1][r] = f.y;
            Ws[kc + 2][r] = f.z; Ws[kc + 3][r] = f.w;
        }
        __syncthreads();
#pragma unroll
        for (int k = 0; k < BKK; k++) {
            float xr[8], wr[8];
            *(float4*)&xr[0] = *(const float4*)&Xs[k][ty * 8];
            *(float4*)&xr[4] = *(const float4*)&Xs[k][ty * 8 + 4];
            *(float4*)&wr[0] = *(const float4*)&Ws[k][tx * 8];
            *(float4*)&wr[4] = *(const float4*)&Ws[k][tx * 8 + 4];
#pragma unroll
            for (int i = 0; i < 8; i++)
#pragma unroll
                for (int j = 0; j < 8; j++)
                    acc[i][j] = fmaf(xr[i], wr[j], acc[i][j]);
        }
        __syncthreads();
    }

#pragma unroll
    for (int i = 0; i < 8; i++) {
        int m = m0 + ty * 8 + i;
        if (m < M) {
#pragma unroll
            for (int j = 0; j < 8; j++) {
                int n = n0 + tx * 8 + j;
                if (n < Nout) {
                    float v = acc[i][j] + (bias ? bias[n] : 0.f);
                    size_t idx = (size_t)m * Nout + n;
                    if (ACT == 1) v = v > 0.f ? v : 0.01f * v;
                    else if (ACT == 2) v = fmaxf(v, 0.f);
                    Y[idx] = v;
                }
            }
        }
    }
}

// ---------------- f16 MFMA GEMM, global_load_lds staging, LDS dbuf ----------------
// Y[m,n] = op( sum_k A[m,k]*B[n,k] + bias[n] )
// A [M,K] f16 row-major, B [Nout,K] f16 row-major
// MODE 0: Y = act(v); 1: Y += v; 2: Y *= sigmoid(v)
// ACT: 0 none, 1 leaky, 2 relu, 3 tanh
// OUT: 0 fp32 only, 1 fp32 + f16 shadow, 2 f16 only (MODE 0 only)
template<int MODE, int ACT, int OUT>
__global__ __launch_bounds__(256)
void mgemm(const _Float16* __restrict__ A, const _Float16* __restrict__ B,
           const float* __restrict__ bias, float* __restrict__ Y,
           _Float16* __restrict__ Yh, int M, int K, int Nout)
{
    __shared__ _Float16 As[2][TBM * TBK];
    __shared__ _Float16 Bs[2][TBM * TBK];
    const int tid = threadIdx.x;
    const int lane = tid & 63;
    const int wid = tid >> 6;
    const int wr = wid >> 1, wc = wid & 1;
    const int m0 = blockIdx.y * TBM;
    const int n0 = blockIdx.x * TBN;

    f32x4 acc[4][4] = {};
    const int nt = K / TBK;

    // per-lane global offsets for staging (chunk c: rows c*16..c*16+15, 4 lanes/row)
    const int lrow = lane >> 2;          // 0..15 row within chunk
    const int lk = (lane & 3) * 8;       // f16 offset within 32-elem k slab

    auto stage = [&](int t, int buf) {
        const int k0 = t * TBK;
#pragma unroll
        for (int q = 0; q < 2; q++) {
            int c = wid * 2 + q;                      // 0..7
            int r = c * 16 + lrow;
            int am = min(m0 + r, M - 1);
            int bn = min(n0 + r, Nout - 1);
            gll16(A + (size_t)am * K + k0 + lk, &As[buf][c * 512]);
            gll16(B + (size_t)bn * K + k0 + lk, &Bs[buf][c * 512]);
        }
    };

    stage(0, 0);
    __syncthreads();
    for (int t = 0; t < nt; ++t) {
        const int cur = t & 1;
        if (t + 1 < nt) stage(t + 1, cur ^ 1);
        f16x8 af[4], bf[4];
#pragma unroll
        for (int mi = 0; mi < 4; mi++)
            af[mi] = *(const f16x8*)(&As[cur][(wr * 64 + mi * 16 + (lane & 15)) * TBK + (lane >> 4) * 8]);
#pragma unroll
        for (int nj = 0; nj < 4; nj++)
            bf[nj] = *(const f16x8*)(&Bs[cur][(wc * 64 + nj * 16 + (lane & 15)) * TBK + (lane >> 4) * 8]);
#pragma unroll
        for (int mi = 0; mi < 4; mi++)
#pragma unroll
            for (int nj = 0; nj < 4; nj++)
                acc[mi][nj] = __builtin_amdgcn_mfma_f32_16x16x32_f16(af[mi], bf[nj], acc[mi][nj], 0, 0, 0);
        __syncthreads();   // drains vmcnt (next-tile staging) + protects buf reuse
    }

#pragma unroll
    for (int mi = 0; mi < 4; mi++) {
        int mbase = m0 + wr * 64 + mi * 16 + (lane >> 4) * 4;
#pragma unroll
        for (int nj = 0; nj < 4; nj++) {
            int n = n0 + wc * 64 + nj * 16 + (lane & 15);
            if (n < Nout) {
                float bv = bias ? bias[n] : 0.f;
#pragma unroll
                for (int r = 0; r < 4; r++) {
                    int m = mbase + r;
                    if (m < M) {
                        float v = acc[mi][nj][r] + bv;
                        size_t idx = (size_t)m * Nout + n;
                        if (MODE == 0) {
                            if (ACT == 1) v = v > 0.f ? v : 0.01f * v;
                            else if (ACT == 2) v = fmaxf(v, 0.f);
                            else if (ACT == 3) v = tanhf(v);
                            if (OUT != 2) Y[idx] = v;
                            if (OUT != 0) Yh[idx] = (_Float16)v;
                        } else if (MODE == 1) {
                            float s = Y[idx] + v;
                            Y[idx] = s;
                            if (OUT != 0) Yh[idx] = (_Float16)s;
                        } else {
                            float s = Y[idx] * (1.f / (1.f + expf(-v)));
                            Y[idx] = s;
                            if (OUT != 0) Yh[idx] = (_Float16)s;
                        }
                    }
                }
            }
        }
    }
}

// ---------------- converters ----------------
__global__ __launch_bounds__(256)
void cvt_k(const float* __restrict__ x, _Float16* __restrict__ y, int n)
{
    int i = (blockIdx.x * 256 + threadIdx.x) * 4;
    if (i < n) {
        float4 v = *(const float4*)(x + i);
        f16x4 h = { (_Float16)v.x, (_Float16)v.y, (_Float16)v.z, (_Float16)v.w };
        *(f16x4*)(y + i) = h;
    }
}

__global__ __launch_bounds__(256)
void cvtC_k(const float* __restrict__ C, _Float16* __restrict__ Ch,
            _Float16* __restrict__ CTh, int Kin)
{
    int i = blockIdx.x * 256 + threadIdx.x;
    if (i < Kin * 512) {
        int j = i >> 9, d = i & 511;
        float v = C[i];
        Ch[i] = (_Float16)v;
        CTh[d * Kin + j] = (_Float16)v;
    }
}

// ---------------- small kernels ----------------
__global__ __launch_bounds__(256)
void rowsq_k(const float* __restrict__ X, float* __restrict__ out, int M)
{
    int wid = threadIdx.x >> 6, lane = threadIdx.x & 63;
    int row = blockIdx.x * 4 + wid;
    if (row >= M) return;
    const float* xr = X + (size_t)row * 512;
    float s = 0.f;
#pragma unroll
    for (int t = 0; t < 2; t++) {
        float4 a = *(const float4*)(xr + t * 256 + lane * 4);
        s += a.x * a.x + a.y * a.y + a.z * a.z + a.w * a.w;
    }
#pragma unroll
    for (int o = 32; o; o >>= 1) s += __shfl_xor(s, o);
    if (lane == 0) out[row] = s;
}

__global__ __launch_bounds__(256)
void soft_k(const float* __restrict__ S, const float* __restrict__ Psq,
            const float* __restrict__ Csq, const float* __restrict__ sim_scale,
            _Float16* __restrict__ Ah, int M, int K)
{
    int wid = threadIdx.x >> 6, lane = threadIdx.x & 63;
    int row = blockIdx.x * 4 + wid;
    if (row >= M) return;
    float denom = fmaxf(1e-6f, sim_scale[0]);
    float pp = Psq[row];
    const float* sr = S + (size_t)row * K;
    float v0 = -INFINITY, v1 = -INFINITY;
    if (lane < K)      v0 = -sqrtf(fmaxf(pp + Csq[lane]      - 2.f * sr[lane],      1e-12f)) / denom;
    if (lane + 64 < K) v1 = -sqrtf(fmaxf(pp + Csq[lane + 64] - 2.f * sr[lane + 64], 1e-12f)) / denom;
    float mx = fmaxf(v0, v1);
#pragma unroll
    for (int o = 32; o; o >>= 1) mx = fmaxf(mx, __shfl_xor(mx, o));
    float e0 = (lane < K) ? expf(v0 - mx) : 0.f;
    float e1 = (lane + 64 < K) ? expf(v1 - mx) : 0.f;
    float s = e0 + e1;
#pragma unroll
    for (int o = 32; o; o >>= 1) s += __shfl_xor(s, o);
    float inv = 1.f / s;
    _Float16* ar = Ah + (size_t)row * K;
    if (lane < K)      ar[lane]      = (_Float16)(e0 * inv);
    if (lane + 64 < K) ar[lane + 64] = (_Float16)(e1 * inv);
}

__global__ __launch_bounds__(256)
void ln_k(const float* __restrict__ X, const float* __restrict__ R,
          const float* __restrict__ g, const float* __restrict__ b,
          float* __restrict__ Y, _Float16* __restrict__ Yh, int M)
{
    int wid = threadIdx.x >> 6, lane = threadIdx.x & 63;
    int row = blockIdx.x * 4 + wid;
    if (row >= M) return;
    const float* xr = X + (size_t)row * 512;
    float v[8];
    float s = 0.f, ss = 0.f;
#pragma unroll
    for (int t = 0; t < 2; t++) {
        float4 a = *(const float4*)(xr + t * 256 + lane * 4);
        if (R) {
            float4 c = *(const float4*)(R + (size_t)row * 512 + t * 256 + lane * 4);
            a.x += c.x; a.y += c.y; a.z += c.z; a.w += c.w;
        }
        v[4 * t + 0] = a.x; v[4 * t + 1] = a.y; v[4 * t + 2] = a.z; v[4 * t + 3] = a.w;
    }
#pragma unroll
    for (int q = 0; q < 8; q++) { s += v[q]; ss += v[q] * v[q]; }
#pragma unroll
    for (int o = 32; o; o >>= 1) { s += __shfl_xor(s, o); ss += __shfl_xor(ss, o); }
    float mean = s * (1.f / 512.f);
    float var = ss * (1.f / 512.f) - mean * mean;
    float inv = 1.f / sqrtf(var + 1e-5f);
    float* yr = Y + (size_t)row * 512;
#pragma unroll
    for (int t = 0; t < 2; t++) {
        int d0 = t * 256 + lane * 4;
        float4 o4;
        o4.x = (v[4 * t + 0] - mean) * inv * g[d0 + 0] + b[d0 + 0];
        o4.y = (v[4 * t + 1] - mean) * inv * g[d0 + 1] + b[d0 + 1];
        o4.z = (v[4 * t + 2] - mean) * inv * g[d0 + 2] + b[d0 + 2];
        o4.w = (v[4 * t + 3] - mean) * inv * g[d0 + 3] + b[d0 + 3];
        *(float4*)(yr + d0) = o4;
        if (Yh) {
            f16x4 h = { (_Float16)o4.x, (_Float16)o4.y, (_Float16)o4.z, (_Float16)o4.w };
            *(f16x4*)(Yh + (size_t)row * 512 + d0) = h;
        }
    }
}

__global__ __launch_bounds__(256)
void red1_k(const float* __restrict__ C, const float* __restrict__ w1,
            const float* __restrict__ b1, float* __restrict__ H1, int Kin)
{
    int d = blockIdx.x * 256 + threadIdx.x;
    int j = blockIdx.y;
    float acc = b1[j];
    for (int k = 0; k < Kin; k++) acc = fmaf(C[(size_t)k * 512 + d], w1[(size_t)j * Kin + k], acc);
    H1[(size_t)j * 512 + d] = fmaxf(acc, 0.f);
}

__global__ __launch_bounds__(256)
void red2_k(const float* __restrict__ H1, const float* __restrict__ w2,
            const float* __restrict__ b2, float* __restrict__ Cn, int Kin, int Kout)
{
    int d = blockIdx.x * 256 + threadIdx.x;
    int j2 = blockIdx.y;
    float acc = b2[j2];
    for (int j = 0; j < Kin; j++) acc = fmaf(H1[(size_t)j * 512 + d], w2[(size_t)j2 * Kin + j], acc);
    Cn[(size_t)j2 * 512 + d] = acc;
}

__global__ __launch_bounds__(256)
void score_k(const float* __restrict__ TG, const float* __restrict__ Ws,
             const float* __restrict__ bs, float* __restrict__ out, int M)
{
    int wid = threadIdx.x >> 6, lane = threadIdx.x & 63;
    int row = blockIdx.x * 4 + wid;
    if (row >= M) return;
    const float* xr = TG + (size_t)row * 512;
    float d = 0.f;
#pragma unroll
    for (int t = 0; t < 2; t++) {
        float4 a = *(const float4*)(xr + t * 256 + lane * 4);
        float4 w = *(const float4*)(Ws + t * 256 + lane * 4);
        d += a.x * w.x + a.y * w.y + a.z * w.z + a.w * w.w;
    }
#pragma unroll
    for (int o = 32; o; o >>= 1) d += __shfl_xor(d, o);
    if (lane == 0) out[row] = d + bs[0];
}

__global__ __launch_bounds__(1024)
void pool_k(float* __restrict__ s, float* __restrict__ scal, int M)
{
    __shared__ float sm[16];
    int tid = threadIdx.x, lane = tid & 63, wid = tid >> 6;
    float mx = -INFINITY;
    for (int i = tid; i < M; i += 1024) mx = fmaxf(mx, s[i]);
#pragma unroll
    for (int o = 32; o; o >>= 1) mx = fmaxf(mx, __shfl_xor(mx, o));
    if (lane == 0) sm[wid] = mx;
    __syncthreads();
    if (wid == 0) {
        float v = (lane < 16) ? sm[lane] : -INFINITY;
#pragma unroll
        for (int o = 8; o; o >>= 1) v = fmaxf(v, __shfl_xor(v, o));
        if (lane == 0) sm[0] = v;
    }
    __syncthreads();
    float gmax = sm[0];
    __syncthreads();
    float sum = 0.f;
    for (int i = tid; i < M; i += 1024) {
        float e = expf(s[i] - gmax);
        s[i] = e;
        sum += e;
    }
#pragma unroll
    for (int o = 32; o; o >>= 1) sum += __shfl_xor(sum, o);
    if (lane == 0) sm[wid] = sum;
    __syncthreads();
    if (tid == 0) {
        float t = 0.f;
        for (int w = 0; w < 16; w++) t += sm[w];
        scal[0] = t;
    }
}

// partial bag over 256 chunks: PB[chunk,d] = sum_{i in chunk} w[i]*Z[i,d]
__global__ __launch_bounds__(256)
void bagp_k(const float* __restrict__ Z, const float* __restrict__ w,
            float* __restrict__ PB, int M, int cs)
{
    int d = blockIdx.x * 256 + threadIdx.x;
    int chunk = blockIdx.y;
    int i0 = chunk * cs;
    int i1 = min(M, i0 + cs);
    float acc = 0.f;
    for (int i = i0; i < i1; i++) acc = fmaf(w[i], Z[(size_t)i * 512 + d], acc);
    PB[(size_t)chunk * 512 + d] = acc;
}

__global__ __launch_bounds__(256)
void bagf_k(const float* __restrict__ PB, const float* __restrict__ scal,
            float* __restrict__ bag, int nchunk)
{
    int d = blockIdx.x * 256 + threadIdx.x;
    float acc = 0.f;
    for (int c = 0; c < nchunk; c++) acc += PB[(size_t)c * 512 + d];
    bag[d] = acc / scal[0];
}

__global__ __launch_bounds__(256)
void h_k(const float* __restrict__ bag, const float* __restrict__ Wh,
         const float* __restrict__ bh, float* __restrict__ h)
{
    int wid = threadIdx.x >> 6, lane = threadIdx.x & 63;
    int j = blockIdx.x * 4 + wid;
    const float* wr = Wh + (size_t)j * 512;
    float d = 0.f;
#pragma unroll
    for (int t = 0; t < 2; t++) {
        float4 a = *(const float4*)(wr + t * 256 + lane * 4);
        float4 bv = *(const float4*)(bag + t * 256 + lane * 4);
        d += a.x * bv.x + a.y * bv.y + a.z * bv.z + a.w * bv.w;
    }
#pragma unroll
    for (int o = 32; o; o >>= 1) d += __shfl_xor(d, o);
    if (lane == 0) h[j] = fmaxf(d + bh[j], 0.f);
}

__global__ __launch_bounds__(128)
void logit_k(const float* __restrict__ h, const float* __restrict__ Wc,
             const float* __restrict__ bc, float* __restrict__ out)
{
    int wid = threadIdx.x >> 6, lane = threadIdx.x & 63;
    const float* wr = Wc + (size_t)wid * 512;
    float d = 0.f;
#pragma unroll
    for (int t = 0; t < 2; t++) {
        float4 a = *(const float4*)(wr + t * 256 + lane * 4);
        float4 hv = *(const float4*)(h + t * 256 + lane * 4);
        d += a.x * hv.x + a.y * hv.y + a.z * hv.z + a.w * hv.w;
    }
#pragma unroll
    for (int o = 32; o; o >>= 1) d += __shfl_xor(d, o);
    if (lane == 0) out[wid] = d + bc[wid];
}

extern "C" void kernel_launch(void* const* d_in, const int* in_sizes, int n_in,
                              void* d_out, int out_size, void* d_ws, size_t ws_size,
                              hipStream_t stream)
{
    const float* data    = (const float*)d_in[0];
    const float* protos  = (const float*)d_in[1];
    const float* W_pp    = (const float*)d_in[2];
    const float* b_pp    = (const float*)d_in[3];
    const float* W_cp    = (const float*)d_in[4];
    const float* b_cp    = (const float*)d_in[5];
    const float* sscale  = (const float*)d_in[6];
    const float* enh_w1  = (const float*)d_in[7];
    const float* enh_b1  = (const float*)d_in[8];
    const float* enh_w2  = (const float*)d_in[9];
    const float* enh_b2  = (const float*)d_in[10];
    const float* ln_g    = (const float*)d_in[11];
    const float* ln_b    = (const float*)d_in[12];
    const float* red_w1[3] = {(const float*)d_in[13], (const float*)d_in[17], (const float*)d_in[21]};
    const float* red_b1[3] = {(const float*)d_in[14], (const float*)d_in[18], (const float*)d_in[22]};
    const float* red_w2[3] = {(const float*)d_in[15], (const float*)d_in[19], (const float*)d_in[23]};
    const float* red_b2[3] = {(const float*)d_in[16], (const float*)d_in[20], (const float*)d_in[24]};
    const float* W_proc  = (const float*)d_in[25];
    const float* b_proc  = (const float*)d_in[26];
    const float* g_an    = (const float*)d_in[27];
    const float* b_an    = (const float*)d_in[28];
    const float* W_t     = (const float*)d_in[29];
    const float* b_t     = (const float*)d_in[30];
    const float* W_g     = (const float*)d_in[31];
    const float* b_g     = (const float*)d_in[32];
    const float* W_s     = (const float*)d_in[33];
    const float* b_s     = (const float*)d_in[34];
    const float* W_h     = (const float*)d_in[35];
    const float* b_h     = (const float*)d_in[36];
    const float* W_c     = (const float*)d_in[37];
    const float* b_c     = (const float*)d_in[38];
    float* out = (float*)d_out;

    constexpr int N = 32768, DIN = 768, D = 512;
    constexpr int NCHUNK = 256;
    char* w = (char*)d_ws;
    auto alloc = [&](size_t bytes) -> char* {
        char* p = w; w += (bytes + 255) & ~(size_t)255; return p;
    };
    float*    P      = (float*)alloc((size_t)N * D * 4);
    float*    TMP    = (float*)alloc((size_t)(N + 16) * D * 4);
    float*    Z      = (float*)alloc((size_t)(N + 16) * D * 4);
    _Float16* Ph     = (_Float16*)alloc((size_t)N * D * 2);
    _Float16* Zh     = (_Float16*)alloc((size_t)(N + 16) * D * 2);
    _Float16* Ah     = (_Float16*)alloc((size_t)N * 128 * 2);
    _Float16* Ch     = (_Float16*)alloc(128 * D * 2);
    _Float16* CTh    = (_Float16*)alloc(128 * D * 2);
    _Float16* Wpph   = (_Float16*)alloc((size_t)D * DIN * 2);
    _Float16* w1h    = (_Float16*)alloc((size_t)3 * D * D * 2);
    _Float16* w2h    = (_Float16*)alloc((size_t)3 * D * D * 2);
    _Float16* Wproch = (_Float16*)alloc((size_t)D * D * 2);
    _Float16* Wth    = (_Float16*)alloc((size_t)D * D * 2);
    _Float16* Wgh    = (_Float16*)alloc((size_t)D * D * 2);
    float*    Psq    = (float*)alloc((size_t)N * 4);
    float*    Csq    = (float*)alloc(128 * 4);
    float*    Ca     = (float*)alloc(128 * D * 4);
    float*    Cb     = (float*)alloc(128 * D * 4);
    float*    H1     = (float*)alloc(128 * D * 4);
    float*    scr    = (float*)alloc((size_t)(N + 16) * 4);
    float*    PB     = (float*)alloc((size_t)NCHUNK * D * 4);
    float*    bag    = (float*)alloc(D * 4);
    float*    hb     = (float*)alloc(D * 4);
    float*    scal   = (float*)alloc(8 * 4);
    // aliases (lifetimes disjoint)
    _Float16* datah  = (_Float16*)Z;      // data f16, dead before Z written
    float*    S      = TMP;               // sim matrix, dead before ctx written
    _Float16* TMPh   = (_Float16*)TMP;    // enh hidden f16, after ctx consumed

    dim3 blk(256);
    auto cgrid = [](size_t n) { return dim3((unsigned)((n / 4 + 255) / 256)); };
    auto mgrid = [](int M_, int Nout_) { return dim3((Nout_ + TBN - 1) / TBN, (M_ + TBM - 1) / TBM); };

    // --- convert weights + data to f16 ---
    cvt_k<<<cgrid((size_t)N * DIN), blk, 0, stream>>>(data, datah, N * DIN);
    cvt_k<<<cgrid((size_t)D * DIN), blk, 0, stream>>>(W_pp, Wpph, D * DIN);
    cvt_k<<<cgrid((size_t)3 * D * D), blk, 0, stream>>>(enh_w1, w1h, 3 * D * D);
    cvt_k<<<cgrid((size_t)3 * D * D), blk, 0, stream>>>(enh_w2, w2h, 3 * D * D);
    cvt_k<<<cgrid((size_t)D * D), blk, 0, stream>>>(W_proc, Wproch, D * D);
    cvt_k<<<cgrid((size_t)D * D), blk, 0, stream>>>(W_t, Wth, D * D);
    cvt_k<<<cgrid((size_t)D * D), blk, 0, stream>>>(W_g, Wgh, D * D);

    // P = leaky(data @ W_pp^T + b_pp)  (fp32 + f16 shadow)
    mgemm<0, 1, 1><<<mgrid(N, D), blk, 0, stream>>>(datah, Wpph, b_pp, P, Ph, N, DIN, D);
    // C0 = leaky(protos @ W_cp^T + b_cp)  (fp32, small)
    gemm_k<true, 0, 1><<<dim3(4, 1), blk, 0, stream>>>(protos, W_cp, b_cp, Ca, 128, DIN, D);

    float* C = Ca;
    float* Cn = Cb;
    int Kin = 128;
    for (int i = 0; i < 3; i++) {
        int Kout = Kin >> 1;
        rowsq_k<<<dim3((N + 3) / 4), blk, 0, stream>>>(P, Psq, N);
        rowsq_k<<<dim3((Kin + 3) / 4), blk, 0, stream>>>(C, Csq, Kin);
        cvtC_k<<<dim3((Kin * D + 255) / 256), blk, 0, stream>>>(C, Ch, CTh, Kin);
        // S = P @ C^T
        mgemm<0, 0, 0><<<mgrid(N, Kin), blk, 0, stream>>>(Ph, Ch, nullptr, S, nullptr, N, D, Kin);
        // A = softmax(-dist/denom) -> f16
        soft_k<<<dim3((N + 3) / 4), blk, 0, stream>>>(S, Psq, Csq, sscale, Ah, N, Kin);
        // ctx = A @ C
        mgemm<0, 0, 0><<<mgrid(N, D), blk, 0, stream>>>(Ah, CTh, nullptr, TMP, nullptr, N, Kin, D);
        // P = LN(P + ctx)
        ln_k<<<dim3((N + 3) / 4), blk, 0, stream>>>(P, TMP, ln_g + (size_t)i * D, ln_b + (size_t)i * D, P, Ph, N);
        // enhancer MLP
        mgemm<0, 2, 2><<<mgrid(N, D), blk, 0, stream>>>(Ph, w1h + (size_t)i * D * D, enh_b1 + (size_t)i * D, nullptr, TMPh, N, D, D);
        mgemm<1, 0, 1><<<mgrid(N, D), blk, 0, stream>>>(TMPh, w2h + (size_t)i * D * D, enh_b2 + (size_t)i * D, P, Ph, N, D, D);
        // ProtoReducer (fp32, tiny)
        red1_k<<<dim3(2, Kin), blk, 0, stream>>>(C, red_w1[i], red_b1[i], H1, Kin);
        red2_k<<<dim3(2, Kout), blk, 0, stream>>>(H1, red_w2[i], red_b2[i], Cn, Kin, Kout);
        float* t = C; C = Cn; Cn = t;
        Kin = Kout;
    }

    // Z = relu(proc([P; C]))
    mgemm<0, 2, 0><<<mgrid(N, D), blk, 0, stream>>>(Ph, Wproch, b_proc, Z, nullptr, N, D, D);
    gemm_k<true, 0, 2><<<dim3(4, 1), blk, 0, stream>>>(C, W_proc, b_proc, Z + (size_t)N * D, 16, D, D);
    ln_k<<<dim3((N + 16 + 3) / 4), blk, 0, stream>>>(Z, nullptr, g_an, b_an, Z, Zh, N + 16);

    // TG = tanh(Z@W_t^T+b_t) * sigmoid(Z@W_g^T+b_g)
    mgemm<0, 3, 0><<<mgrid(N + 16, D), blk, 0, stream>>>(Zh, Wth, b_t, TMP, nullptr, N + 16, D, D);
    mgemm<2, 0, 0><<<mgrid(N + 16, D), blk, 0, stream>>>(Zh, Wgh, b_g, TMP, nullptr, N + 16, D, D);

    // attention pooling
    score_k<<<dim3((N + 16 + 3) / 4), blk, 0, stream>>>(TMP, W_s, b_s, scr, N + 16);
    pool_k<<<dim3(1), dim3(1024), 0, stream>>>(scr, scal, N + 16);
    int cs = (N + 16 + NCHUNK - 1) / NCHUNK;
    bagp_k<<<dim3(2, NCHUNK), blk, 0, stream>>>(Z, scr, PB, N + 16, cs);
    bagf_k<<<dim3(2), blk, 0, stream>>>(PB, scal, bag, NCHUNK);

    // classifier head
    h_k<<<dim3(128), blk, 0, stream>>>(bag, W_h, b_h, hb);
    logit_k<<<dim3(1), dim3(128), 0, stream>>>(hb, W_c, b_c, out);
}

// Round 4
// 1302.286 us; speedup vs baseline: 2.7910x; 1.1480x over previous
//
#include <hip/hip_runtime.h>
#include <math.h>

typedef _Float16 f16x8 __attribute__((ext_vector_type(8)));
typedef _Float16 f16x4 __attribute__((ext_vector_type(4)));
typedef float f32x4 __attribute__((ext_vector_type(4)));

#define TBM 128
#define TBN 128
#define TBK 32

#define AS1 __attribute__((address_space(1)))
#define AS3 __attribute__((address_space(3)))

__device__ __forceinline__ void gll16(const _Float16* g, _Float16* l)
{
    // direct global->LDS, 16B per lane; LDS dest = wave-uniform base + lane*16
    __builtin_amdgcn_global_load_lds((const AS1 unsigned int*)g,
                                     (AS3 unsigned int*)l, 16, 0, 0);
}

// ---------------- wave-per-output dot kernel (small-M fp32 GEMMs) ----------------
// Y[r,n] = act( dot(X[r,:], W[n,:]) + bias[n] ), Nout fixed = 512
// ACT: 1 leaky, 2 relu
template<int ACT>
__global__ __launch_bounds__(256)
void dot_k(const float* __restrict__ X, const float* __restrict__ W,
           const float* __restrict__ bias, float* __restrict__ Y,
           int M, int K)
{
    int gw = (blockIdx.x * 256 + threadIdx.x) >> 6;
    int lane = threadIdx.x & 63;
    if (gw >= M * 512) return;
    int r = gw >> 9, n = gw & 511;
    const float* xr = X + (size_t)r * K;
    const float* wr = W + (size_t)n * K;
    float d = 0.f;
    for (int t = 0; t < K; t += 256) {
        float4 a = *(const float4*)(xr + t + lane * 4);
        float4 b = *(const float4*)(wr + t + lane * 4);
        d += a.x * b.x + a.y * b.y + a.z * b.z + a.w * b.w;
    }
#pragma unroll
    for (int o = 32; o; o >>= 1) d += __shfl_xor(d, o);
    if (lane == 0) {
        float v = d + bias[n];
        if (ACT == 1) v = v > 0.f ? v : 0.01f * v;
        else if (ACT == 2) v = fmaxf(v, 0.f);
        Y[(size_t)r * 512 + n] = v;
    }
}

// ---------------- f16 MFMA GEMM, global_load_lds staging, LDS dbuf ----------------
// Y[m,n] = op( sum_k A[m,k]*B[n,k] + bias[n] )
// MODE 0: Y = act(v); 1: Y += v; 2: Y *= sigmoid(v)
// ACT: 0 none, 1 leaky, 2 relu, 3 tanh
// OUT: 0 fp32 only, 1 fp32 + f16 shadow, 2 f16 only (MODE 0 only)
template<int MODE, int ACT, int OUT>
__global__ __launch_bounds__(256)
void mgemm(const _Float16* __restrict__ A, const _Float16* __restrict__ B,
           const float* __restrict__ bias, float* __restrict__ Y,
           _Float16* __restrict__ Yh, int M, int K, int Nout)
{
    __shared__ _Float16 As[2][TBM * TBK];
    __shared__ _Float16 Bs[2][TBM * TBK];
    const int tid = threadIdx.x;
    const int lane = tid & 63;
    const int wid = tid >> 6;
    const int wr = wid >> 1, wc = wid & 1;
    const int m0 = blockIdx.y * TBM;
    const int n0 = blockIdx.x * TBN;

    f32x4 acc[4][4] = {};
    const int nt = K / TBK;

    const int lrow = lane >> 2;          // 0..15 row within chunk
    const int lk = (lane & 3) * 8;       // f16 offset within 32-elem k slab

    auto stage = [&](int t, int buf) {
        const int k0 = t * TBK;
#pragma unroll
        for (int q = 0; q < 2; q++) {
            int c = wid * 2 + q;                      // 0..7
            int r = c * 16 + lrow;
            int am = min(m0 + r, M - 1);
            int bn = min(n0 + r, Nout - 1);
            gll16(A + (size_t)am * K + k0 + lk, &As[buf][c * 512]);
            gll16(B + (size_t)bn * K + k0 + lk, &Bs[buf][c * 512]);
        }
    };

    stage(0, 0);
    __syncthreads();
    for (int t = 0; t < nt; ++t) {
        const int cur = t & 1;
        if (t + 1 < nt) stage(t + 1, cur ^ 1);
        f16x8 af[4], bf[4];
#pragma unroll
        for (int mi = 0; mi < 4; mi++)
            af[mi] = *(const f16x8*)(&As[cur][(wr * 64 + mi * 16 + (lane & 15)) * TBK + (lane >> 4) * 8]);
#pragma unroll
        for (int nj = 0; nj < 4; nj++)
            bf[nj] = *(const f16x8*)(&Bs[cur][(wc * 64 + nj * 16 + (lane & 15)) * TBK + (lane >> 4) * 8]);
#pragma unroll
        for (int mi = 0; mi < 4; mi++)
#pragma unroll
            for (int nj = 0; nj < 4; nj++)
                acc[mi][nj] = __builtin_amdgcn_mfma_f32_16x16x32_f16(af[mi], bf[nj], acc[mi][nj], 0, 0, 0);
        __syncthreads();   // drains vmcnt (next-tile staging) + protects buf reuse
    }

#pragma unroll
    for (int mi = 0; mi < 4; mi++) {
        int mbase = m0 + wr * 64 + mi * 16 + (lane >> 4) * 4;
#pragma unroll
        for (int nj = 0; nj < 4; nj++) {
            int n = n0 + wc * 64 + nj * 16 + (lane & 15);
            if (n < Nout) {
                float bv = bias ? bias[n] : 0.f;
#pragma unroll
                for (int r = 0; r < 4; r++) {
                    int m = mbase + r;
                    if (m < M) {
                        float v = acc[mi][nj][r] + bv;
                        size_t idx = (size_t)m * Nout + n;
                        if (MODE == 0) {
                            if (ACT == 1) v = v > 0.f ? v : 0.01f * v;
                            else if (ACT == 2) v = fmaxf(v, 0.f);
                            else if (ACT == 3) v = tanhf(v);
                            if (OUT != 2) Y[idx] = v;
                            if (OUT != 0) Yh[idx] = (_Float16)v;
                        } else if (MODE == 1) {
                            float s = Y[idx] + v;
                            Y[idx] = s;
                            if (OUT != 0) Yh[idx] = (_Float16)s;
                        } else {
                            float s = Y[idx] * (1.f / (1.f + expf(-v)));
                            Y[idx] = s;
                            if (OUT != 0) Yh[idx] = (_Float16)s;
                        }
                    }
                }
            }
        }
    }
}

// ---------------- converters ----------------
__global__ __launch_bounds__(256)
void cvt_k(const float* __restrict__ x, _Float16* __restrict__ y, int n)
{
    int i = (blockIdx.x * 256 + threadIdx.x) * 4;
    if (i < n) {
        float4 v = *(const float4*)(x + i);
        f16x4 h = { (_Float16)v.x, (_Float16)v.y, (_Float16)v.z, (_Float16)v.w };
        *(f16x4*)(y + i) = h;
    }
}

__global__ __launch_bounds__(256)
void cvtC_k(const float* __restrict__ C, _Float16* __restrict__ Ch,
            _Float16* __restrict__ CTh, int Kin)
{
    int i = blockIdx.x * 256 + threadIdx.x;
    if (i < Kin * 512) {
        int j = i >> 9, d = i & 511;
        float v = C[i];
        Ch[i] = (_Float16)v;
        CTh[d * Kin + j] = (_Float16)v;
    }
}

// ---------------- small kernels ----------------
__global__ __launch_bounds__(256)
void rowsq_k(const float* __restrict__ X, float* __restrict__ out, int M)
{
    int wid = threadIdx.x >> 6, lane = threadIdx.x & 63;
    int row = blockIdx.x * 4 + wid;
    if (row >= M) return;
    const float* xr = X + (size_t)row * 512;
    float s = 0.f;
#pragma unroll
    for (int t = 0; t < 2; t++) {
        float4 a = *(const float4*)(xr + t * 256 + lane * 4);
        s += a.x * a.x + a.y * a.y + a.z * a.z + a.w * a.w;
    }
#pragma unroll
    for (int o = 32; o; o >>= 1) s += __shfl_xor(s, o);
    if (lane == 0) out[row] = s;
}

__global__ __launch_bounds__(256)
void soft_k(const float* __restrict__ S, const float* __restrict__ Psq,
            const float* __restrict__ Csq, const float* __restrict__ sim_scale,
            _Float16* __restrict__ Ah, int M, int K)
{
    int wid = threadIdx.x >> 6, lane = threadIdx.x & 63;
    int row = blockIdx.x * 4 + wid;
    if (row >= M) return;
    float denom = fmaxf(1e-6f, sim_scale[0]);
    float pp = Psq[row];
    const float* sr = S + (size_t)row * K;
    float v0 = -INFINITY, v1 = -INFINITY;
    if (lane < K)      v0 = -sqrtf(fmaxf(pp + Csq[lane]      - 2.f * sr[lane],      1e-12f)) / denom;
    if (lane + 64 < K) v1 = -sqrtf(fmaxf(pp + Csq[lane + 64] - 2.f * sr[lane + 64], 1e-12f)) / denom;
    float mx = fmaxf(v0, v1);
#pragma unroll
    for (int o = 32; o; o >>= 1) mx = fmaxf(mx, __shfl_xor(mx, o));
    float e0 = (lane < K) ? expf(v0 - mx) : 0.f;
    float e1 = (lane + 64 < K) ? expf(v1 - mx) : 0.f;
    float s = e0 + e1;
#pragma unroll
    for (int o = 32; o; o >>= 1) s += __shfl_xor(s, o);
    float inv = 1.f / s;
    _Float16* ar = Ah + (size_t)row * K;
    if (lane < K)      ar[lane]      = (_Float16)(e0 * inv);
    if (lane + 64 < K) ar[lane + 64] = (_Float16)(e1 * inv);
}

__global__ __launch_bounds__(256)
void ln_k(const float* __restrict__ X, const float* __restrict__ R,
          const float* __restrict__ g, const float* __restrict__ b,
          float* __restrict__ Y, _Float16* __restrict__ Yh, int M)
{
    int wid = threadIdx.x >> 6, lane = threadIdx.x & 63;
    int row = blockIdx.x * 4 + wid;
    if (row >= M) return;
    const float* xr = X + (size_t)row * 512;
    float v[8];
    float s = 0.f, ss = 0.f;
#pragma unroll
    for (int t = 0; t < 2; t++) {
        float4 a = *(const float4*)(xr + t * 256 + lane * 4);
        if (R) {
            float4 c = *(const float4*)(R + (size_t)row * 512 + t * 256 + lane * 4);
            a.x += c.x; a.y += c.y; a.z += c.z; a.w += c.w;
        }
        v[4 * t + 0] = a.x; v[4 * t + 1] = a.y; v[4 * t + 2] = a.z; v[4 * t + 3] = a.w;
    }
#pragma unroll
    for (int q = 0; q < 8; q++) { s += v[q]; ss += v[q] * v[q]; }
#pragma unroll
    for (int o = 32; o; o >>= 1) { s += __shfl_xor(s, o); ss += __shfl_xor(ss, o); }
    float mean = s * (1.f / 512.f);
    float var = ss * (1.f / 512.f) - mean * mean;
    float inv = 1.f / sqrtf(var + 1e-5f);
    float* yr = Y + (size_t)row * 512;
#pragma unroll
    for (int t = 0; t < 2; t++) {
        int d0 = t * 256 + lane * 4;
        float4 o4;
        o4.x = (v[4 * t + 0] - mean) * inv * g[d0 + 0] + b[d0 + 0];
        o4.y = (v[4 * t + 1] - mean) * inv * g[d0 + 1] + b[d0 + 1];
        o4.z = (v[4 * t + 2] - mean) * inv * g[d0 + 2] + b[d0 + 2];
        o4.w = (v[4 * t + 3] - mean) * inv * g[d0 + 3] + b[d0 + 3];
        *(float4*)(yr + d0) = o4;
        if (Yh) {
            f16x4 h = { (_Float16)o4.x, (_Float16)o4.y, (_Float16)o4.z, (_Float16)o4.w };
            *(f16x4*)(Yh + (size_t)row * 512 + d0) = h;
        }
    }
}

__global__ __launch_bounds__(256)
void red1_k(const float* __restrict__ C, const float* __restrict__ w1,
            const float* __restrict__ b1, float* __restrict__ H1, int Kin)
{
    int d = blockIdx.x * 256 + threadIdx.x;
    int j = blockIdx.y;
    float acc = b1[j];
    for (int k = 0; k < Kin; k++) acc = fmaf(C[(size_t)k * 512 + d], w1[(size_t)j * Kin + k], acc);
    H1[(size_t)j * 512 + d] = fmaxf(acc, 0.f);
}

__global__ __launch_bounds__(256)
void red2_k(const float* __restrict__ H1, const float* __restrict__ w2,
            const float* __restrict__ b2, float* __restrict__ Cn, int Kin, int Kout)
{
    int d = blockIdx.x * 256 + threadIdx.x;
    int j2 = blockIdx.y;
    float acc = b2[j2];
    for (int j = 0; j < Kin; j++) acc = fmaf(H1[(size_t)j * 512 + d], w2[(size_t)j2 * Kin + j], acc);
    Cn[(size_t)j2 * 512 + d] = acc;
}

__global__ __launch_bounds__(256)
void score_k(const float* __restrict__ TG, const float* __restrict__ Ws,
             const float* __restrict__ bs, float* __restrict__ out, int M)
{
    int wid = threadIdx.x >> 6, lane = threadIdx.x & 63;
    int row = blockIdx.x * 4 + wid;
    if (row >= M) return;
    const float* xr = TG + (size_t)row * 512;
    float d = 0.f;
#pragma unroll
    for (int t = 0; t < 2; t++) {
        float4 a = *(const float4*)(xr + t * 256 + lane * 4);
        float4 w = *(const float4*)(Ws + t * 256 + lane * 4);
        d += a.x * w.x + a.y * w.y + a.z * w.z + a.w * w.w;
    }
#pragma unroll
    for (int o = 32; o; o >>= 1) d += __shfl_xor(d, o);
    if (lane == 0) out[row] = d + bs[0];
}

// single block, ILP via independent float4 chunks
__global__ __launch_bounds__(1024)
void pool_k(float* __restrict__ s, float* __restrict__ scal, int M)
{
    __shared__ float sm[16];
    int tid = threadIdx.x, lane = tid & 63, wid = tid >> 6;
    float mx = -INFINITY;
    for (int i = tid * 4; i < M; i += 4096) {
        float4 a = *(const float4*)(s + i);
        mx = fmaxf(fmaxf(fmaxf(mx, a.x), fmaxf(a.y, a.z)), a.w);
    }
#pragma unroll
    for (int o = 32; o; o >>= 1) mx = fmaxf(mx, __shfl_xor(mx, o));
    if (lane == 0) sm[wid] = mx;
    __syncthreads();
    if (wid == 0) {
        float v = (lane < 16) ? sm[lane] : -INFINITY;
#pragma unroll
        for (int o = 8; o; o >>= 1) v = fmaxf(v, __shfl_xor(v, o));
        if (lane == 0) sm[0] = v;
    }
    __syncthreads();
    float gmax = sm[0];
    __syncthreads();
    float sum = 0.f;
    for (int i = tid * 4; i < M; i += 4096) {
        float4 a = *(const float4*)(s + i);
        float4 e;
        e.x = expf(a.x - gmax); e.y = expf(a.y - gmax);
        e.z = expf(a.z - gmax); e.w = expf(a.w - gmax);
        *(float4*)(s + i) = e;
        sum += e.x + e.y + e.z + e.w;
    }
#pragma unroll
    for (int o = 32; o; o >>= 1) sum += __shfl_xor(sum, o);
    if (lane == 0) sm[wid] = sum;
    __syncthreads();
    if (tid == 0) {
        float t = 0.f;
        for (int w = 0; w < 16; w++) t += sm[w];
        scal[0] = t;
    }
}

__global__ __launch_bounds__(256)
void bagp_k(const float* __restrict__ Z, const float* __restrict__ w,
            float* __restrict__ PB, int M, int cs)
{
    int d = blockIdx.x * 256 + threadIdx.x;
    int chunk = blockIdx.y;
    int i0 = chunk * cs;
    int i1 = min(M, i0 + cs);
    float acc = 0.f;
    for (int i = i0; i < i1; i++) acc = fmaf(w[i], Z[(size_t)i * 512 + d], acc);
    PB[(size_t)chunk * 512 + d] = acc;
}

__global__ __launch_bounds__(256)
void bagf_k(const float* __restrict__ PB, const float* __restrict__ scal,
            float* __restrict__ bag, int nchunk)
{
    int d = blockIdx.x * 256 + threadIdx.x;
    float acc = 0.f;
    for (int c = 0; c < nchunk; c++) acc += PB[(size_t)c * 512 + d];
    bag[d] = acc / scal[0];
}

__global__ __launch_bounds__(256)
void h_k(const float* __restrict__ bag, const float* __restrict__ Wh,
         const float* __restrict__ bh, float* __restrict__ h)
{
    int wid = threadIdx.x >> 6, lane = threadIdx.x & 63;
    int j = blockIdx.x * 4 + wid;
    const float* wr = Wh + (size_t)j * 512;
    float d = 0.f;
#pragma unroll
    for (int t = 0; t < 2; t++) {
        float4 a = *(const float4*)(wr + t * 256 + lane * 4);
        float4 bv = *(const float4*)(bag + t * 256 + lane * 4);
        d += a.x * bv.x + a.y * bv.y + a.z * bv.z + a.w * bv.w;
    }
#pragma unroll
    for (int o = 32; o; o >>= 1) d += __shfl_xor(d, o);
    if (lane == 0) h[j] = fmaxf(d + bh[j], 0.f);
}

__global__ __launch_bounds__(128)
void logit_k(const float* __restrict__ h, const float* __restrict__ Wc,
             const float* __restrict__ bc, float* __restrict__ out)
{
    int wid = threadIdx.x >> 6, lane = threadIdx.x & 63;
    const float* wr = Wc + (size_t)wid * 512;
    float d = 0.f;
#pragma unroll
    for (int t = 0; t < 2; t++) {
        float4 a = *(const float4*)(wr + t * 256 + lane * 4);
        float4 hv = *(const float4*)(h + t * 256 + lane * 4);
        d += a.x * hv.x + a.y * hv.y + a.z * hv.z + a.w * hv.w;
    }
#pragma unroll
    for (int o = 32; o; o >>= 1) d += __shfl_xor(d, o);
    if (lane == 0) out[wid] = d + bc[wid];
}

extern "C" void kernel_launch(void* const* d_in, const int* in_sizes, int n_in,
                              void* d_out, int out_size, void* d_ws, size_t ws_size,
                              hipStream_t stream)
{
    const float* data    = (const float*)d_in[0];
    const float* protos  = (const float*)d_in[1];
    const float* W_pp    = (const float*)d_in[2];
    const float* b_pp    = (const float*)d_in[3];
    const float* W_cp    = (const float*)d_in[4];
    const float* b_cp    = (const float*)d_in[5];
    const float* sscale  = (const float*)d_in[6];
    const float* enh_w1  = (const float*)d_in[7];
    const float* enh_b1  = (const float*)d_in[8];
    const float* enh_w2  = (const float*)d_in[9];
    const float* enh_b2  = (const float*)d_in[10];
    const float* ln_g    = (const float*)d_in[11];
    const float* ln_b    = (const float*)d_in[12];
    const float* red_w1[3] = {(const float*)d_in[13], (const float*)d_in[17], (const float*)d_in[21]};
    const float* red_b1[3] = {(const float*)d_in[14], (const float*)d_in[18], (const float*)d_in[22]};
    const float* red_w2[3] = {(const float*)d_in[15], (const float*)d_in[19], (const float*)d_in[23]};
    const float* red_b2[3] = {(const float*)d_in[16], (const float*)d_in[20], (const float*)d_in[24]};
    const float* W_proc  = (const float*)d_in[25];
    const float* b_proc  = (const float*)d_in[26];
    const float* g_an    = (const float*)d_in[27];
    const float* b_an    = (const float*)d_in[28];
    const float* W_t     = (const float*)d_in[29];
    const float* b_t     = (const float*)d_in[30];
    const float* W_g     = (const float*)d_in[31];
    const float* b_g     = (const float*)d_in[32];
    const float* W_s     = (const float*)d_in[33];
    const float* b_s     = (const float*)d_in[34];
    const float* W_h     = (const float*)d_in[35];
    const float* b_h     = (const float*)d_in[36];
    const float* W_c     = (const float*)d_in[37];
    const float* b_c     = (const float*)d_in[38];
    float* out = (float*)d_out;

    constexpr int N = 32768, DIN = 768, D = 512;
    constexpr int NCHUNK = 256;
    char* w = (char*)d_ws;
    auto alloc = [&](size_t bytes) -> char* {
        char* p = w; w += (bytes + 255) & ~(size_t)255; return p;
    };
    float*    P      = (float*)alloc((size_t)N * D * 4);
    float*    TMP    = (float*)alloc((size_t)(N + 16) * D * 4);
    float*    Z      = (float*)alloc((size_t)(N + 16) * D * 4);
    _Float16* Ph     = (_Float16*)alloc((size_t)N * D * 2);
    _Float16* Zh     = (_Float16*)alloc((size_t)(N + 16) * D * 2);
    _Float16* Ah     = (_Float16*)alloc((size_t)N * 128 * 2);
    _Float16* Ch     = (_Float16*)alloc(128 * D * 2);
    _Float16* CTh    = (_Float16*)alloc(128 * D * 2);
    _Float16* Wpph   = (_Float16*)alloc((size_t)D * DIN * 2);
    _Float16* w1h    = (_Float16*)alloc((size_t)3 * D * D * 2);
    _Float16* w2h    = (_Float16*)alloc((size_t)3 * D * D * 2);
    _Float16* Wproch = (_Float16*)alloc((size_t)D * D * 2);
    _Float16* Wth    = (_Float16*)alloc((size_t)D * D * 2);
    _Float16* Wgh    = (_Float16*)alloc((size_t)D * D * 2);
    float*    Psq    = (float*)alloc((size_t)N * 4);
    float*    Csq    = (float*)alloc(128 * 4);
    float*    Ca     = (float*)alloc(128 * D * 4);
    float*    Cb     = (float*)alloc(128 * D * 4);
    float*    H1     = (float*)alloc(128 * D * 4);
    float*    scr    = (float*)alloc((size_t)(N + 16) * 4);
    float*    PB     = (float*)alloc((size_t)NCHUNK * D * 4);
    float*    bag    = (float*)alloc(D * 4);
    float*    hb     = (float*)alloc(D * 4);
    float*    scal   = (float*)alloc(8 * 4);
    // aliases (lifetimes disjoint)
    _Float16* datah  = (_Float16*)Z;      // data f16, dead before Z written
    float*    S      = TMP;               // sim matrix, dead before ctx written
    _Float16* TMPh   = (_Float16*)TMP;    // enh hidden f16, after ctx consumed

    dim3 blk(256);
    auto cgrid = [](size_t n) { return dim3((unsigned)((n / 4 + 255) / 256)); };
    auto mgrid = [](int M_, int Nout_) { return dim3((Nout_ + TBN - 1) / TBN, (M_ + TBM - 1) / TBM); };

    // --- convert weights + data to f16 ---
    cvt_k<<<cgrid((size_t)N * DIN), blk, 0, stream>>>(data, datah, N * DIN);
    cvt_k<<<cgrid((size_t)D * DIN), blk, 0, stream>>>(W_pp, Wpph, D * DIN);
    cvt_k<<<cgrid((size_t)3 * D * D), blk, 0, stream>>>(enh_w1, w1h, 3 * D * D);
    cvt_k<<<cgrid((size_t)3 * D * D), blk, 0, stream>>>(enh_w2, w2h, 3 * D * D);
    cvt_k<<<cgrid((size_t)D * D), blk, 0, stream>>>(W_proc, Wproch, D * D);
    cvt_k<<<cgrid((size_t)D * D), blk, 0, stream>>>(W_t, Wth, D * D);
    cvt_k<<<cgrid((size_t)D * D), blk, 0, stream>>>(W_g, Wgh, D * D);

    // P = leaky(data @ W_pp^T + b_pp)  (fp32 + f16 shadow)
    mgemm<0, 1, 1><<<mgrid(N, D), blk, 0, stream>>>(datah, Wpph, b_pp, P, Ph, N, DIN, D);
    // C0 = leaky(protos @ W_cp^T + b_cp)  (fp32, wave-per-dot: 128*512 waves)
    dot_k<1><<<dim3(128 * 512 / 4), blk, 0, stream>>>(protos, W_cp, b_cp, Ca, 128, DIN);

    float* C = Ca;
    float* Cn = Cb;
    int Kin = 128;
    for (int i = 0; i < 3; i++) {
        int Kout = Kin >> 1;
        rowsq_k<<<dim3((N + 3) / 4), blk, 0, stream>>>(P, Psq, N);
        rowsq_k<<<dim3((Kin + 3) / 4), blk, 0, stream>>>(C, Csq, Kin);
        cvtC_k<<<dim3((Kin * D + 255) / 256), blk, 0, stream>>>(C, Ch, CTh, Kin);
        // S = P @ C^T
        mgemm<0, 0, 0><<<mgrid(N, Kin), blk, 0, stream>>>(Ph, Ch, nullptr, S, nullptr, N, D, Kin);
        // A = softmax(-dist/denom) -> f16
        soft_k<<<dim3((N + 3) / 4), blk, 0, stream>>>(S, Psq, Csq, sscale, Ah, N, Kin);
        // ctx = A @ C
        mgemm<0, 0, 0><<<mgrid(N, D), blk, 0, stream>>>(Ah, CTh, nullptr, TMP, nullptr, N, Kin, D);
        // P = LN(P + ctx)
        ln_k<<<dim3((N + 3) / 4), blk, 0, stream>>>(P, TMP, ln_g + (size_t)i * D, ln_b + (size_t)i * D, P, Ph, N);
        // enhancer MLP
        mgemm<0, 2, 2><<<mgrid(N, D), blk, 0, stream>>>(Ph, w1h + (size_t)i * D * D, enh_b1 + (size_t)i * D, nullptr, TMPh, N, D, D);
        mgemm<1, 0, 1><<<mgrid(N, D), blk, 0, stream>>>(TMPh, w2h + (size_t)i * D * D, enh_b2 + (size_t)i * D, P, Ph, N, D, D);
        // ProtoReducer (fp32, tiny)
        red1_k<<<dim3(2, Kin), blk, 0, stream>>>(C, red_w1[i], red_b1[i], H1, Kin);
        red2_k<<<dim3(2, Kout), blk, 0, stream>>>(H1, red_w2[i], red_b2[i], Cn, Kin, Kout);
        float* t = C; C = Cn; Cn = t;
        Kin = Kout;
    }

    // Z = relu(proc([P; C]))
    mgemm<0, 2, 0><<<mgrid(N, D), blk, 0, stream>>>(Ph, Wproch, b_proc, Z, nullptr, N, D, D);
    dot_k<2><<<dim3(16 * 512 / 4), blk, 0, stream>>>(C, W_proc, b_proc, Z + (size_t)N * D, 16, D);
    ln_k<<<dim3((N + 16 + 3) / 4), blk, 0, stream>>>(Z, nullptr, g_an, b_an, Z, Zh, N + 16);

    // TG = tanh(Z@W_t^T+b_t) * sigmoid(Z@W_g^T+b_g)
    mgemm<0, 3, 0><<<mgrid(N + 16, D), blk, 0, stream>>>(Zh, Wth, b_t, TMP, nullptr, N + 16, D, D);
    mgemm<2, 0, 0><<<mgrid(N + 16, D), blk, 0, stream>>>(Zh, Wgh, b_g, TMP, nullptr, N + 16, D, D);

    // attention pooling
    score_k<<<dim3((N + 16 + 3) / 4), blk, 0, stream>>>(TMP, W_s, b_s, scr, N + 16);
    pool_k<<<dim3(1), dim3(1024), 0, stream>>>(scr, scal, N + 16);
    int cs = (N + 16 + NCHUNK - 1) / NCHUNK;
    bagp_k<<<dim3(2, NCHUNK), blk, 0, stream>>>(Z, scr, PB, N + 16, cs);
    bagf_k<<<dim3(2), blk, 0, stream>>>(PB, scal, bag, NCHUNK);

    // classifier head
    h_k<<<dim3(128), blk, 0, stream>>>(bag, W_h, b_h, hb);
    logit_k<<<dim3(1), dim3(128), 0, stream>>>(hb, W_c, b_c, out);
}

// Round 5
// 1146.193 us; speedup vs baseline: 3.1711x; 1.1362x over previous
//
#include <hip/hip_runtime.h>
#include <math.h>

typedef _Float16 f16x8 __attribute__((ext_vector_type(8)));
typedef _Float16 f16x4 __attribute__((ext_vector_type(4)));
typedef float f32x4 __attribute__((ext_vector_type(4)));

#define TBM 128
#define TBN 128
#define TBK 32

#define AS1 __attribute__((address_space(1)))
#define AS3 __attribute__((address_space(3)))

__device__ __forceinline__ void gll16(const _Float16* g, _Float16* l)
{
    // direct global->LDS, 16B per lane; LDS dest = wave-uniform base + lane*16
    __builtin_amdgcn_global_load_lds((const AS1 unsigned int*)g,
                                     (AS3 unsigned int*)l, 16, 0, 0);
}

// ---------------- wave-per-output dot kernel (small-M fp32 GEMMs) ----------------
// Y[r,n] = act( dot(X[r,:], W[n,:]) + bias[n] ), Nout = 512
// ACT: 1 leaky, 2 relu ; F16OUT selects output dtype
template<int ACT, bool F16OUT>
__global__ __launch_bounds__(256)
void dot_k(const float* __restrict__ X, const float* __restrict__ W,
           const float* __restrict__ bias, void* __restrict__ Yv,
           int M, int K)
{
    int gw = (blockIdx.x * 256 + threadIdx.x) >> 6;
    int lane = threadIdx.x & 63;
    if (gw >= M * 512) return;
    int r = gw >> 9, n = gw & 511;
    const float* xr = X + (size_t)r * K;
    const float* wr = W + (size_t)n * K;
    float d = 0.f;
    for (int t = 0; t < K; t += 256) {
        float4 a = *(const float4*)(xr + t + lane * 4);
        float4 b = *(const float4*)(wr + t + lane * 4);
        d += a.x * b.x + a.y * b.y + a.z * b.z + a.w * b.w;
    }
#pragma unroll
    for (int o = 32; o; o >>= 1) d += __shfl_xor(d, o);
    if (lane == 0) {
        float v = d + bias[n];
        if (ACT == 1) v = v > 0.f ? v : 0.01f * v;
        else if (ACT == 2) v = fmaxf(v, 0.f);
        if (F16OUT) ((_Float16*)Yv)[(size_t)r * 512 + n] = (_Float16)v;
        else        ((float*)Yv)[(size_t)r * 512 + n] = v;
    }
}

// ---------------- f16 MFMA GEMM, global_load_lds staging, LDS dbuf ----------------
// v[m,n] = sum_k A[m,k]*B[n,k] + bias[n]
// MODE 0: out = act(v)            -> Yh f16  (or Yf fp32 if F32OUT)
// MODE 1: out = Yh + v            -> Yh f16  (residual accumulate, fp32 add)
// MODE 2: out = Yh * sigmoid(v)   -> Yh f16
// ACT: 0 none, 1 leaky, 2 relu, 3 tanh
template<int MODE, int ACT, bool F32OUT>
__global__ __launch_bounds__(256)
void mgemm(const _Float16* __restrict__ A, const _Float16* __restrict__ B,
           const float* __restrict__ bias, _Float16* __restrict__ Yh,
           float* __restrict__ Yf, int M, int K, int Nout)
{
    __shared__ _Float16 As[2][TBM * TBK];
    __shared__ _Float16 Bs[2][TBM * TBK];
    const int tid = threadIdx.x;
    const int lane = tid & 63;
    const int wid = tid >> 6;
    const int wr = wid >> 1, wc = wid & 1;
    const int m0 = blockIdx.y * TBM;
    const int n0 = blockIdx.x * TBN;

    f32x4 acc[4][4] = {};
    const int nt = K / TBK;

    const int lrow = lane >> 2;          // 0..15 row within chunk
    const int lk = (lane & 3) * 8;       // f16 offset within 32-elem k slab

    auto stage = [&](int t, int buf) {
        const int k0 = t * TBK;
#pragma unroll
        for (int q = 0; q < 2; q++) {
            int c = wid * 2 + q;                      // 0..7
            int r = c * 16 + lrow;
            int am = min(m0 + r, M - 1);
            int bn = min(n0 + r, Nout - 1);
            gll16(A + (size_t)am * K + k0 + lk, &As[buf][c * 512]);
            gll16(B + (size_t)bn * K + k0 + lk, &Bs[buf][c * 512]);
        }
    };

    stage(0, 0);
    __syncthreads();
    for (int t = 0; t < nt; ++t) {
        const int cur = t & 1;
        if (t + 1 < nt) stage(t + 1, cur ^ 1);
        f16x8 af[4], bf[4];
#pragma unroll
        for (int mi = 0; mi < 4; mi++)
            af[mi] = *(const f16x8*)(&As[cur][(wr * 64 + mi * 16 + (lane & 15)) * TBK + (lane >> 4) * 8]);
#pragma unroll
        for (int nj = 0; nj < 4; nj++)
            bf[nj] = *(const f16x8*)(&Bs[cur][(wc * 64 + nj * 16 + (lane & 15)) * TBK + (lane >> 4) * 8]);
#pragma unroll
        for (int mi = 0; mi < 4; mi++)
#pragma unroll
            for (int nj = 0; nj < 4; nj++)
                acc[mi][nj] = __builtin_amdgcn_mfma_f32_16x16x32_f16(af[mi], bf[nj], acc[mi][nj], 0, 0, 0);
        __syncthreads();   // drains vmcnt (next-tile staging) + protects buf reuse
    }

#pragma unroll
    for (int mi = 0; mi < 4; mi++) {
        int mbase = m0 + wr * 64 + mi * 16 + (lane >> 4) * 4;
#pragma unroll
        for (int nj = 0; nj < 4; nj++) {
            int n = n0 + wc * 64 + nj * 16 + (lane & 15);
            if (n < Nout) {
                float bv = bias ? bias[n] : 0.f;
#pragma unroll
                for (int r = 0; r < 4; r++) {
                    int m = mbase + r;
                    if (m < M) {
                        float v = acc[mi][nj][r] + bv;
                        size_t idx = (size_t)m * Nout + n;
                        if (MODE == 0) {
                            if (ACT == 1) v = v > 0.f ? v : 0.01f * v;
                            else if (ACT == 2) v = fmaxf(v, 0.f);
                            else if (ACT == 3) v = tanhf(v);
                            if (F32OUT) Yf[idx] = v;
                            else        Yh[idx] = (_Float16)v;
                        } else if (MODE == 1) {
                            float s = (float)Yh[idx] + v;
                            Yh[idx] = (_Float16)s;
                        } else {
                            float s = (float)Yh[idx] * (1.f / (1.f + expf(-v)));
                            Yh[idx] = (_Float16)s;
                        }
                    }
                }
            }
        }
    }
}

// ---------------- converters ----------------
__global__ __launch_bounds__(256)
void cvt_k(const float* __restrict__ x, _Float16* __restrict__ y, int n)
{
    int i = (blockIdx.x * 256 + threadIdx.x) * 4;
    if (i < n) {
        float4 v = *(const float4*)(x + i);
        f16x4 h = { (_Float16)v.x, (_Float16)v.y, (_Float16)v.z, (_Float16)v.w };
        *(f16x4*)(y + i) = h;
    }
}

// C [Kin,512] fp32 -> Ch [Kin,512] f16 and CTh [512,Kin] f16
__global__ __launch_bounds__(256)
void cvtC_k(const float* __restrict__ C, _Float16* __restrict__ Ch,
            _Float16* __restrict__ CTh, int Kin)
{
    int i = blockIdx.x * 256 + threadIdx.x;
    if (i < Kin * 512) {
        int j = i >> 9, d = i & 511;
        float v = C[i];
        Ch[i] = (_Float16)v;
        CTh[d * Kin + j] = (_Float16)v;
    }
}

// ---------------- small kernels (f16 activations) ----------------
// sum of squares per row of [M,512] f16 matrix; one wave per row
__global__ __launch_bounds__(256)
void rowsq_k(const _Float16* __restrict__ X, float* __restrict__ out, int M)
{
    int wid = threadIdx.x >> 6, lane = threadIdx.x & 63;
    int row = blockIdx.x * 4 + wid;
    if (row >= M) return;
    f16x8 a = *(const f16x8*)(X + (size_t)row * 512 + lane * 8);
    float s = 0.f;
#pragma unroll
    for (int q = 0; q < 8; q++) { float f = (float)a[q]; s += f * f; }
#pragma unroll
    for (int o = 32; o; o >>= 1) s += __shfl_xor(s, o);
    if (lane == 0) out[row] = s;
}

__global__ __launch_bounds__(256)
void soft_k(const float* __restrict__ S, const float* __restrict__ Psq,
            const float* __restrict__ Csq, const float* __restrict__ sim_scale,
            _Float16* __restrict__ Ah, int M, int K)
{
    int wid = threadIdx.x >> 6, lane = threadIdx.x & 63;
    int row = blockIdx.x * 4 + wid;
    if (row >= M) return;
    float denom = fmaxf(1e-6f, sim_scale[0]);
    float pp = Psq[row];
    const float* sr = S + (size_t)row * K;
    float v0 = -INFINITY, v1 = -INFINITY;
    if (lane < K)      v0 = -sqrtf(fmaxf(pp + Csq[lane]      - 2.f * sr[lane],      1e-12f)) / denom;
    if (lane + 64 < K) v1 = -sqrtf(fmaxf(pp + Csq[lane + 64] - 2.f * sr[lane + 64], 1e-12f)) / denom;
    float mx = fmaxf(v0, v1);
#pragma unroll
    for (int o = 32; o; o >>= 1) mx = fmaxf(mx, __shfl_xor(mx, o));
    float e0 = (lane < K) ? expf(v0 - mx) : 0.f;
    float e1 = (lane + 64 < K) ? expf(v1 - mx) : 0.f;
    float s = e0 + e1;
#pragma unroll
    for (int o = 32; o; o >>= 1) s += __shfl_xor(s, o);
    float inv = 1.f / s;
    _Float16* ar = Ah + (size_t)row * K;
    if (lane < K)      ar[lane]      = (_Float16)(e0 * inv);
    if (lane + 64 < K) ar[lane + 64] = (_Float16)(e1 * inv);
}

// Yh = LN(X (+R)) * g + b, f16 in/out, fp32 math; one wave per row
__global__ __launch_bounds__(256)
void ln_k(const _Float16* __restrict__ X, const _Float16* __restrict__ R,
          const float* __restrict__ g, const float* __restrict__ b,
          _Float16* __restrict__ Yh, int M)
{
    int wid = threadIdx.x >> 6, lane = threadIdx.x & 63;
    int row = blockIdx.x * 4 + wid;
    if (row >= M) return;
    f16x8 a = *(const f16x8*)(X + (size_t)row * 512 + lane * 8);
    float v[8];
#pragma unroll
    for (int q = 0; q < 8; q++) v[q] = (float)a[q];
    if (R) {
        f16x8 c = *(const f16x8*)(R + (size_t)row * 512 + lane * 8);
#pragma unroll
        for (int q = 0; q < 8; q++) v[q] += (float)c[q];
    }
    float s = 0.f, ss = 0.f;
#pragma unroll
    for (int q = 0; q < 8; q++) { s += v[q]; ss += v[q] * v[q]; }
#pragma unroll
    for (int o = 32; o; o >>= 1) { s += __shfl_xor(s, o); ss += __shfl_xor(ss, o); }
    float mean = s * (1.f / 512.f);
    float var = ss * (1.f / 512.f) - mean * mean;
    float inv = 1.f / sqrtf(var + 1e-5f);
    int d0 = lane * 8;
    f16x8 o8;
#pragma unroll
    for (int q = 0; q < 8; q++)
        o8[q] = (_Float16)((v[q] - mean) * inv * g[d0 + q] + b[d0 + q]);
    *(f16x8*)(Yh + (size_t)row * 512 + d0) = o8;
}

__global__ __launch_bounds__(256)
void red1_k(const float* __restrict__ C, const float* __restrict__ w1,
            const float* __restrict__ b1, float* __restrict__ H1, int Kin)
{
    int d = blockIdx.x * 256 + threadIdx.x;
    int j = blockIdx.y;
    float acc = b1[j];
    for (int k = 0; k < Kin; k++) acc = fmaf(C[(size_t)k * 512 + d], w1[(size_t)j * Kin + k], acc);
    H1[(size_t)j * 512 + d] = fmaxf(acc, 0.f);
}

__global__ __launch_bounds__(256)
void red2_k(const float* __restrict__ H1, const float* __restrict__ w2,
            const float* __restrict__ b2, float* __restrict__ Cn, int Kin, int Kout)
{
    int d = blockIdx.x * 256 + threadIdx.x;
    int j2 = blockIdx.y;
    float acc = b2[j2];
    for (int j = 0; j < Kin; j++) acc = fmaf(H1[(size_t)j * 512 + d], w2[(size_t)j2 * Kin + j], acc);
    Cn[(size_t)j2 * 512 + d] = acc;
}

// scores[i] = dot(TG[i,:], Ws) + bs; TG f16
__global__ __launch_bounds__(256)
void score_k(const _Float16* __restrict__ TG, const float* __restrict__ Ws,
             const float* __restrict__ bs, float* __restrict__ out, int M)
{
    int wid = threadIdx.x >> 6, lane = threadIdx.x & 63;
    int row = blockIdx.x * 4 + wid;
    if (row >= M) return;
    f16x8 a = *(const f16x8*)(TG + (size_t)row * 512 + lane * 8);
    float4 w0 = *(const float4*)(Ws + lane * 8);
    float4 w1 = *(const float4*)(Ws + lane * 8 + 4);
    float d = (float)a[0] * w0.x + (float)a[1] * w0.y + (float)a[2] * w0.z + (float)a[3] * w0.w
            + (float)a[4] * w1.x + (float)a[5] * w1.y + (float)a[6] * w1.z + (float)a[7] * w1.w;
#pragma unroll
    for (int o = 32; o; o >>= 1) d += __shfl_xor(d, o);
    if (lane == 0) out[row] = d + bs[0];
}

// single block, ILP via independent float4 chunks
__global__ __launch_bounds__(1024)
void pool_k(float* __restrict__ s, float* __restrict__ scal, int M)
{
    __shared__ float sm[16];
    int tid = threadIdx.x, lane = tid & 63, wid = tid >> 6;
    float mx = -INFINITY;
    for (int i = tid * 4; i < M; i += 4096) {
        float4 a = *(const float4*)(s + i);
        mx = fmaxf(fmaxf(fmaxf(mx, a.x), fmaxf(a.y, a.z)), a.w);
    }
#pragma unroll
    for (int o = 32; o; o >>= 1) mx = fmaxf(mx, __shfl_xor(mx, o));
    if (lane == 0) sm[wid] = mx;
    __syncthreads();
    if (wid == 0) {
        float v = (lane < 16) ? sm[lane] : -INFINITY;
#pragma unroll
        for (int o = 8; o; o >>= 1) v = fmaxf(v, __shfl_xor(v, o));
        if (lane == 0) sm[0] = v;
    }
    __syncthreads();
    float gmax = sm[0];
    __syncthreads();
    float sum = 0.f;
    for (int i = tid * 4; i < M; i += 4096) {
        float4 a = *(const float4*)(s + i);
        float4 e;
        e.x = expf(a.x - gmax); e.y = expf(a.y - gmax);
        e.z = expf(a.z - gmax); e.w = expf(a.w - gmax);
        *(float4*)(s + i) = e;
        sum += e.x + e.y + e.z + e.w;
    }
#pragma unroll
    for (int o = 32; o; o >>= 1) sum += __shfl_xor(sum, o);
    if (lane == 0) sm[wid] = sum;
    __syncthreads();
    if (tid == 0) {
        float t = 0.f;
        for (int w = 0; w < 16; w++) t += sm[w];
        scal[0] = t;
    }
}

// partial bag: PB[chunk,d] = sum_{i in chunk} w[i]*Z[i,d] ; Z f16
__global__ __launch_bounds__(256)
void bagp_k(const _Float16* __restrict__ Z, const float* __restrict__ w,
            float* __restrict__ PB, int M, int cs)
{
    int d = blockIdx.x * 256 + threadIdx.x;
    int chunk = blockIdx.y;
    int i0 = chunk * cs;
    int i1 = min(M, i0 + cs);
    float acc = 0.f;
    for (int i = i0; i < i1; i++) acc = fmaf(w[i], (float)Z[(size_t)i * 512 + d], acc);
    PB[(size_t)chunk * 512 + d] = acc;
}

__global__ __launch_bounds__(256)
void bagf_k(const float* __restrict__ PB, const float* __restrict__ scal,
            float* __restrict__ bag, int nchunk)
{
    int d = blockIdx.x * 256 + threadIdx.x;
    float acc = 0.f;
    for (int c = 0; c < nchunk; c++) acc += PB[(size_t)c * 512 + d];
    bag[d] = acc / scal[0];
}

__global__ __launch_bounds__(256)
void h_k(const float* __restrict__ bag, const float* __restrict__ Wh,
         const float* __restrict__ bh, float* __restrict__ h)
{
    int wid = threadIdx.x >> 6, lane = threadIdx.x & 63;
    int j = blockIdx.x * 4 + wid;
    const float* wr = Wh + (size_t)j * 512;
    float d = 0.f;
#pragma unroll
    for (int t = 0; t < 2; t++) {
        float4 a = *(const float4*)(wr + t * 256 + lane * 4);
        float4 bv = *(const float4*)(bag + t * 256 + lane * 4);
        d += a.x * bv.x + a.y * bv.y + a.z * bv.z + a.w * bv.w;
    }
#pragma unroll
    for (int o = 32; o; o >>= 1) d += __shfl_xor(d, o);
    if (lane == 0) h[j] = fmaxf(d + bh[j], 0.f);
}

__global__ __launch_bounds__(128)
void logit_k(const float* __restrict__ h, const float* __restrict__ Wc,
             const float* __restrict__ bc, float* __restrict__ out)
{
    int wid = threadIdx.x >> 6, lane = threadIdx.x & 63;
    const float* wr = Wc + (size_t)wid * 512;
    float d = 0.f;
#pragma unroll
    for (int t = 0; t < 2; t++) {
        float4 a = *(const float4*)(wr + t * 256 + lane * 4);
        float4 hv = *(const float4*)(h + t * 256 + lane * 4);
        d += a.x * hv.x + a.y * hv.y + a.z * hv.z + a.w * hv.w;
    }
#pragma unroll
    for (int o = 32; o; o >>= 1) d += __shfl_xor(d, o);
    if (lane == 0) out[wid] = d + bc[wid];
}

extern "C" void kernel_launch(void* const* d_in, const int* in_sizes, int n_in,
                              void* d_out, int out_size, void* d_ws, size_t ws_size,
                              hipStream_t stream)
{
    const float* data    = (const float*)d_in[0];
    const float* protos  = (const float*)d_in[1];
    const float* W_pp    = (const float*)d_in[2];
    const float* b_pp    = (const float*)d_in[3];
    const float* W_cp    = (const float*)d_in[4];
    const float* b_cp    = (const float*)d_in[5];
    const float* sscale  = (const float*)d_in[6];
    const float* enh_w1  = (const float*)d_in[7];
    const float* enh_b1  = (const float*)d_in[8];
    const float* enh_w2  = (const float*)d_in[9];
    const float* enh_b2  = (const float*)d_in[10];
    const float* ln_g    = (const float*)d_in[11];
    const float* ln_b    = (const float*)d_in[12];
    const float* red_w1[3] = {(const float*)d_in[13], (const float*)d_in[17], (const float*)d_in[21]};
    const float* red_b1[3] = {(const float*)d_in[14], (const float*)d_in[18], (const float*)d_in[22]};
    const float* red_w2[3] = {(const float*)d_in[15], (const float*)d_in[19], (const float*)d_in[23]};
    const float* red_b2[3] = {(const float*)d_in[16], (const float*)d_in[20], (const float*)d_in[24]};
    const float* W_proc  = (const float*)d_in[25];
    const float* b_proc  = (const float*)d_in[26];
    const float* g_an    = (const float*)d_in[27];
    const float* b_an    = (const float*)d_in[28];
    const float* W_t     = (const float*)d_in[29];
    const float* b_t     = (const float*)d_in[30];
    const float* W_g     = (const float*)d_in[31];
    const float* b_g     = (const float*)d_in[32];
    const float* W_s     = (const float*)d_in[33];
    const float* b_s     = (const float*)d_in[34];
    const float* W_h     = (const float*)d_in[35];
    const float* b_h     = (const float*)d_in[36];
    const float* W_c     = (const float*)d_in[37];
    const float* b_c     = (const float*)d_in[38];
    float* out = (float*)d_out;

    constexpr int N = 32768, DIN = 768, D = 512;
    constexpr int NCHUNK = 256;
    char* w = (char*)d_ws;
    auto alloc = [&](size_t bytes) -> char* {
        char* p = w; w += (bytes + 255) & ~(size_t)255; return p;
    };
    _Float16* Ph     = (_Float16*)alloc((size_t)N * D * 2);          // P activations (f16 master)
    _Float16* CTXh   = (_Float16*)alloc((size_t)N * D * 2);          // ctx
    _Float16* TMPh   = (_Float16*)alloc((size_t)N * D * 2);          // enh hidden
    _Float16* Zrawh  = (_Float16*)alloc((size_t)(N + 16) * D * 2);   // pre-LN Z
    _Float16* Zh     = (_Float16*)alloc((size_t)(N + 16) * D * 2);   // LN'd Z
    _Float16* TGh    = (_Float16*)alloc((size_t)(N + 16) * D * 2);   // tanh*sig
    _Float16* datah  = (_Float16*)alloc((size_t)N * DIN * 2);
    _Float16* Ah     = (_Float16*)alloc((size_t)N * 128 * 2);
    float*    S      = (float*)alloc((size_t)N * 128 * 4);
    _Float16* Ch     = (_Float16*)alloc(128 * D * 2);
    _Float16* CTh    = (_Float16*)alloc(128 * D * 2);
    _Float16* Wpph   = (_Float16*)alloc((size_t)D * DIN * 2);
    _Float16* w1h    = (_Float16*)alloc((size_t)3 * D * D * 2);
    _Float16* w2h    = (_Float16*)alloc((size_t)3 * D * D * 2);
    _Float16* Wproch = (_Float16*)alloc((size_t)D * D * 2);
    _Float16* Wth    = (_Float16*)alloc((size_t)D * D * 2);
    _Float16* Wgh    = (_Float16*)alloc((size_t)D * D * 2);
    float*    Psq    = (float*)alloc((size_t)N * 4);
    float*    Csq    = (float*)alloc(128 * 4);
    float*    Ca     = (float*)alloc(128 * D * 4);
    float*    Cb     = (float*)alloc(128 * D * 4);
    float*    H1     = (float*)alloc(128 * D * 4);
    float*    scr    = (float*)alloc((size_t)(N + 16) * 4);
    float*    PB     = (float*)alloc((size_t)NCHUNK * D * 4);
    float*    bag    = (float*)alloc(D * 4);
    float*    hb     = (float*)alloc(D * 4);
    float*    scal   = (float*)alloc(8 * 4);

    dim3 blk(256);
    auto cgrid = [](size_t n) { return dim3((unsigned)((n / 4 + 255) / 256)); };
    auto mgrid = [](int M_, int Nout_) { return dim3((Nout_ + TBN - 1) / TBN, (M_ + TBM - 1) / TBM); };

    // --- convert weights + data to f16 ---
    cvt_k<<<cgrid((size_t)N * DIN), blk, 0, stream>>>(data, datah, N * DIN);
    cvt_k<<<cgrid((size_t)D * DIN), blk, 0, stream>>>(W_pp, Wpph, D * DIN);
    cvt_k<<<cgrid((size_t)3 * D * D), blk, 0, stream>>>(enh_w1, w1h, 3 * D * D);
    cvt_k<<<cgrid((size_t)3 * D * D), blk, 0, stream>>>(enh_w2, w2h, 3 * D * D);
    cvt_k<<<cgrid((size_t)D * D), blk, 0, stream>>>(W_proc, Wproch, D * D);
    cvt_k<<<cgrid((size_t)D * D), blk, 0, stream>>>(W_t, Wth, D * D);
    cvt_k<<<cgrid((size_t)D * D), blk, 0, stream>>>(W_g, Wgh, D * D);

    // P = leaky(data @ W_pp^T + b_pp) -> f16
    mgemm<0, 1, false><<<mgrid(N, D), blk, 0, stream>>>(datah, Wpph, b_pp, Ph, nullptr, N, DIN, D);
    // C0 = leaky(protos @ W_cp^T + b_cp) -> fp32 (tiny)
    dot_k<1, false><<<dim3(128 * 512 / 4), blk, 0, stream>>>(protos, W_cp, b_cp, Ca, 128, DIN);

    float* C = Ca;
    float* Cn = Cb;
    int Kin = 128;
    for (int i = 0; i < 3; i++) {
        int Kout = Kin >> 1;
        rowsq_k<<<dim3((N + 3) / 4), blk, 0, stream>>>(Ph, Psq, N);
        cvtC_k<<<dim3((Kin * D + 255) / 256), blk, 0, stream>>>(C, Ch, CTh, Kin);
        rowsq_k<<<dim3((Kin + 3) / 4), blk, 0, stream>>>(Ch, Csq, Kin);
        // S = P @ C^T  (fp32 out)
        mgemm<0, 0, true><<<mgrid(N, Kin), blk, 0, stream>>>(Ph, Ch, nullptr, nullptr, S, N, D, Kin);
        // A = softmax(-dist/denom) -> f16
        soft_k<<<dim3((N + 3) / 4), blk, 0, stream>>>(S, Psq, Csq, sscale, Ah, N, Kin);
        // ctx = A @ C -> f16
        mgemm<0, 0, false><<<mgrid(N, D), blk, 0, stream>>>(Ah, CTh, nullptr, CTXh, nullptr, N, Kin, D);
        // P = LN(P + ctx) -> f16
        ln_k<<<dim3((N + 3) / 4), blk, 0, stream>>>(Ph, CTXh, ln_g + (size_t)i * D, ln_b + (size_t)i * D, Ph, N);
        // enhancer MLP: P += w2 @ relu(w1 @ P + b1) + b2
        mgemm<0, 2, false><<<mgrid(N, D), blk, 0, stream>>>(Ph, w1h + (size_t)i * D * D, enh_b1 + (size_t)i * D, TMPh, nullptr, N, D, D);
        mgemm<1, 0, false><<<mgrid(N, D), blk, 0, stream>>>(TMPh, w2h + (size_t)i * D * D, enh_b2 + (size_t)i * D, Ph, nullptr, N, D, D);
        // ProtoReducer (fp32, tiny)
        red1_k<<<dim3(2, Kin), blk, 0, stream>>>(C, red_w1[i], red_b1[i], H1, Kin);
        red2_k<<<dim3(2, Kout), blk, 0, stream>>>(H1, red_w2[i], red_b2[i], Cn, Kin, Kout);
        float* t = C; C = Cn; Cn = t;
        Kin = Kout;
    }

    // Zraw = relu(proc([P; C]))
    mgemm<0, 2, false><<<mgrid(N, D), blk, 0, stream>>>(Ph, Wproch, b_proc, Zrawh, nullptr, N, D, D);
    dot_k<2, true><<<dim3(16 * 512 / 4), blk, 0, stream>>>(C, W_proc, b_proc, Zrawh + (size_t)N * D, 16, D);
    // Z = LN(Zraw)
    ln_k<<<dim3((N + 16 + 3) / 4), blk, 0, stream>>>(Zrawh, nullptr, g_an, b_an, Zh, N + 16);

    // TG = tanh(Z@W_t^T+b_t) * sigmoid(Z@W_g^T+b_g)
    mgemm<0, 3, false><<<mgrid(N + 16, D), blk, 0, stream>>>(Zh, Wth, b_t, TGh, nullptr, N + 16, D, D);
    mgemm<2, 0, false><<<mgrid(N + 16, D), blk, 0, stream>>>(Zh, Wgh, b_g, TGh, nullptr, N + 16, D, D);

    // attention pooling
    score_k<<<dim3((N + 16 + 3) / 4), blk, 0, stream>>>(TGh, W_s, b_s, scr, N + 16);
    pool_k<<<dim3(1), dim3(1024), 0, stream>>>(scr, scal, N + 16);
    int cs = (N + 16 + NCHUNK - 1) / NCHUNK;
    bagp_k<<<dim3(2, NCHUNK), blk, 0, stream>>>(Zh, scr, PB, N + 16, cs);
    bagf_k<<<dim3(2), blk, 0, stream>>>(PB, scal, bag, NCHUNK);

    // classifier head
    h_k<<<dim3(128), blk, 0, stream>>>(bag, W_h, b_h, hb);
    logit_k<<<dim3(1), dim3(128), 0, stream>>>(hb, W_c, b_c, out);
}

// Round 6
// 1114.200 us; speedup vs baseline: 3.2621x; 1.0287x over previous
//
#include <hip/hip_runtime.h>
#include <math.h>

typedef _Float16 f16x8 __attribute__((ext_vector_type(8)));
typedef _Float16 f16x4 __attribute__((ext_vector_type(4)));
typedef float f32x4 __attribute__((ext_vector_type(4)));

#define TBM 128
#define TBN 128
#define TBK 32

#define AS1 __attribute__((address_space(1)))
#define AS3 __attribute__((address_space(3)))

__device__ __forceinline__ void gll16(const _Float16* g, _Float16* l)
{
    // direct global->LDS, 16B per lane; LDS dest = wave-uniform base + lane*16
    __builtin_amdgcn_global_load_lds((const AS1 unsigned int*)g,
                                     (AS3 unsigned int*)l, 16, 0, 0);
}

// XCD-aware bijective swizzle of linear block id (nwg % 8 == 0 required for effect)
__device__ __forceinline__ int xcd_swz(int bid, int nwg)
{
    if ((nwg & 7) == 0) {
        int chunk = nwg >> 3;
        bid = (bid & 7) * chunk + (bid >> 3);
    }
    return bid;
}

// ---------------- wave-per-output dot kernel (small-M fp32 GEMMs) ----------------
// ACT: 1 leaky, 2 relu ; F16OUT selects output dtype
template<int ACT, bool F16OUT>
__global__ __launch_bounds__(256)
void dot_k(const float* __restrict__ X, const float* __restrict__ W,
           const float* __restrict__ bias, void* __restrict__ Yv,
           int M, int K)
{
    int gw = (blockIdx.x * 256 + threadIdx.x) >> 6;
    int lane = threadIdx.x & 63;
    if (gw >= M * 512) return;
    int r = gw >> 9, n = gw & 511;
    const float* xr = X + (size_t)r * K;
    const float* wr = W + (size_t)n * K;
    float d = 0.f;
    for (int t = 0; t < K; t += 256) {
        float4 a = *(const float4*)(xr + t + lane * 4);
        float4 b = *(const float4*)(wr + t + lane * 4);
        d += a.x * b.x + a.y * b.y + a.z * b.z + a.w * b.w;
    }
#pragma unroll
    for (int o = 32; o; o >>= 1) d += __shfl_xor(d, o);
    if (lane == 0) {
        float v = d + bias[n];
        if (ACT == 1) v = v > 0.f ? v : 0.01f * v;
        else if (ACT == 2) v = fmaxf(v, 0.f);
        if (F16OUT) ((_Float16*)Yv)[(size_t)r * 512 + n] = (_Float16)v;
        else        ((float*)Yv)[(size_t)r * 512 + n] = v;
    }
}

// ---------------- f16 MFMA GEMM, global_load_lds staging, LDS dbuf ----------------
// v[m,n] = sum_k A[m,k]*B[n,k] + bias[n]
// MODE 0: out = act(v) -> Yh f16 (or Yf fp32 if F32OUT); MODE 1: out = Yh + v
// ACT: 0 none, 1 leaky, 2 relu, 3 tanh
template<int MODE, int ACT, bool F32OUT>
__global__ __launch_bounds__(256)
void mgemm(const _Float16* __restrict__ A, const _Float16* __restrict__ B,
           const float* __restrict__ bias, _Float16* __restrict__ Yh,
           float* __restrict__ Yf, int M, int K, int Nout)
{
    __shared__ _Float16 As[2][TBM * TBK];
    __shared__ _Float16 Bs[2][TBM * TBK];
    const int tid = threadIdx.x;
    const int lane = tid & 63;
    const int wid = tid >> 6;
    const int wr = wid >> 1, wc = wid & 1;

    int bid = xcd_swz(blockIdx.y * gridDim.x + blockIdx.x, gridDim.x * gridDim.y);
    const int m0 = (bid / gridDim.x) * TBM;
    const int n0 = (bid % gridDim.x) * TBN;

    f32x4 acc[4][4] = {};
    const int nt = K / TBK;

    const int lrow = lane >> 2;          // 0..15 row within chunk
    const int lk = (lane & 3) * 8;       // f16 offset within 32-elem k slab

    auto stage = [&](int t, int buf) {
        const int k0 = t * TBK;
#pragma unroll
        for (int q = 0; q < 2; q++) {
            int c = wid * 2 + q;                      // 0..7
            int r = c * 16 + lrow;
            int am = min(m0 + r, M - 1);
            int bn = min(n0 + r, Nout - 1);
            gll16(A + (size_t)am * K + k0 + lk, &As[buf][c * 512]);
            gll16(B + (size_t)bn * K + k0 + lk, &Bs[buf][c * 512]);
        }
    };

    stage(0, 0);
    __syncthreads();
    for (int t = 0; t < nt; ++t) {
        const int cur = t & 1;
        if (t + 1 < nt) stage(t + 1, cur ^ 1);
        f16x8 af[4], bf[4];
#pragma unroll
        for (int mi = 0; mi < 4; mi++)
            af[mi] = *(const f16x8*)(&As[cur][(wr * 64 + mi * 16 + (lane & 15)) * TBK + (lane >> 4) * 8]);
#pragma unroll
        for (int nj = 0; nj < 4; nj++)
            bf[nj] = *(const f16x8*)(&Bs[cur][(wc * 64 + nj * 16 + (lane & 15)) * TBK + (lane >> 4) * 8]);
#pragma unroll
        for (int mi = 0; mi < 4; mi++)
#pragma unroll
            for (int nj = 0; nj < 4; nj++)
                acc[mi][nj] = __builtin_amdgcn_mfma_f32_16x16x32_f16(af[mi], bf[nj], acc[mi][nj], 0, 0, 0);
        __syncthreads();
    }

#pragma unroll
    for (int mi = 0; mi < 4; mi++) {
        int mbase = m0 + wr * 64 + mi * 16 + (lane >> 4) * 4;
#pragma unroll
        for (int nj = 0; nj < 4; nj++) {
            int n = n0 + wc * 64 + nj * 16 + (lane & 15);
            if (n < Nout) {
                float bv = bias ? bias[n] : 0.f;
#pragma unroll
                for (int r = 0; r < 4; r++) {
                    int m = mbase + r;
                    if (m < M) {
                        float v = acc[mi][nj][r] + bv;
                        size_t idx = (size_t)m * Nout + n;
                        if (MODE == 0) {
                            if (ACT == 1) v = v > 0.f ? v : 0.01f * v;
                            else if (ACT == 2) v = fmaxf(v, 0.f);
                            else if (ACT == 3) v = tanhf(v);
                            if (F32OUT) Yf[idx] = v;
                            else        Yh[idx] = (_Float16)v;
                        } else {
                            float s = (float)Yh[idx] + v;
                            Yh[idx] = (_Float16)s;
                        }
                    }
                }
            }
        }
    }
}

// ---------------- fused dual-projection gate GEMM: TG = tanh(A@B1^T+c1) * sigmoid(A@B2^T+c2) ----------------
__global__ __launch_bounds__(256)
void gatgemm(const _Float16* __restrict__ A, const _Float16* __restrict__ B1,
             const _Float16* __restrict__ B2, const float* __restrict__ c1,
             const float* __restrict__ c2, _Float16* __restrict__ Y,
             int M, int K, int Nout)
{
    __shared__ _Float16 As[2][TBM * TBK];
    __shared__ _Float16 B1s[2][TBM * TBK];
    __shared__ _Float16 B2s[2][TBM * TBK];
    const int tid = threadIdx.x;
    const int lane = tid & 63;
    const int wid = tid >> 6;
    const int wr = wid >> 1, wc = wid & 1;

    int bid = xcd_swz(blockIdx.y * gridDim.x + blockIdx.x, gridDim.x * gridDim.y);
    const int m0 = (bid / gridDim.x) * TBM;
    const int n0 = (bid % gridDim.x) * TBN;

    f32x4 acc1[4][4] = {};
    f32x4 acc2[4][4] = {};
    const int nt = K / TBK;

    const int lrow = lane >> 2;
    const int lk = (lane & 3) * 8;

    auto stage = [&](int t, int buf) {
        const int k0 = t * TBK;
#pragma unroll
        for (int q = 0; q < 2; q++) {
            int c = wid * 2 + q;
            int r = c * 16 + lrow;
            int am = min(m0 + r, M - 1);
            int bn = min(n0 + r, Nout - 1);
            gll16(A + (size_t)am * K + k0 + lk, &As[buf][c * 512]);
            gll16(B1 + (size_t)bn * K + k0 + lk, &B1s[buf][c * 512]);
            gll16(B2 + (size_t)bn * K + k0 + lk, &B2s[buf][c * 512]);
        }
    };

    stage(0, 0);
    __syncthreads();
    for (int t = 0; t < nt; ++t) {
        const int cur = t & 1;
        if (t + 1 < nt) stage(t + 1, cur ^ 1);
        f16x8 af[4], bf1[4], bf2[4];
#pragma unroll
        for (int mi = 0; mi < 4; mi++)
            af[mi] = *(const f16x8*)(&As[cur][(wr * 64 + mi * 16 + (lane & 15)) * TBK + (lane >> 4) * 8]);
#pragma unroll
        for (int nj = 0; nj < 4; nj++) {
            int ro = (wc * 64 + nj * 16 + (lane & 15)) * TBK + (lane >> 4) * 8;
            bf1[nj] = *(const f16x8*)(&B1s[cur][ro]);
            bf2[nj] = *(const f16x8*)(&B2s[cur][ro]);
        }
#pragma unroll
        for (int mi = 0; mi < 4; mi++)
#pragma unroll
            for (int nj = 0; nj < 4; nj++) {
                acc1[mi][nj] = __builtin_amdgcn_mfma_f32_16x16x32_f16(af[mi], bf1[nj], acc1[mi][nj], 0, 0, 0);
                acc2[mi][nj] = __builtin_amdgcn_mfma_f32_16x16x32_f16(af[mi], bf2[nj], acc2[mi][nj], 0, 0, 0);
            }
        __syncthreads();
    }

#pragma unroll
    for (int mi = 0; mi < 4; mi++) {
        int mbase = m0 + wr * 64 + mi * 16 + (lane >> 4) * 4;
#pragma unroll
        for (int nj = 0; nj < 4; nj++) {
            int n = n0 + wc * 64 + nj * 16 + (lane & 15);
            if (n < Nout) {
                float bv1 = c1[n], bv2 = c2[n];
#pragma unroll
                for (int r = 0; r < 4; r++) {
                    int m = mbase + r;
                    if (m < M) {
                        float t1 = tanhf(acc1[mi][nj][r] + bv1);
                        float g1 = 1.f / (1.f + expf(-(acc2[mi][nj][r] + bv2)));
                        Y[(size_t)m * Nout + n] = (_Float16)(t1 * g1);
                    }
                }
            }
        }
    }
}

// ---------------- fused sim GEMM + row softmax (Kin <= 128, grid.x == 1) ----------------
// S = P@C^T ; sim = -sqrt(max(pp+cc-2S,1e-12))/denom ; Ah = softmax_row(sim) f16
__global__ __launch_bounds__(256)
void simgemm(const _Float16* __restrict__ A, const _Float16* __restrict__ B,
             const float* __restrict__ Psq, const float* __restrict__ Csq,
             const float* __restrict__ sscale, _Float16* __restrict__ Ah,
             int M, int K, int Kin)
{
    __shared__ _Float16 As[2][TBM * TBK];
    __shared__ _Float16 Bs[2][TBM * TBK];
    __shared__ float redmx[2][TBM];
    __shared__ float redsm[2][TBM];
    const int tid = threadIdx.x;
    const int lane = tid & 63;
    const int wid = tid >> 6;
    const int wr = wid >> 1, wc = wid & 1;
    const int m0 = blockIdx.y * TBM;

    f32x4 acc[4][4] = {};
    const int nt = K / TBK;
    const int lrow = lane >> 2;
    const int lk = (lane & 3) * 8;

    auto stage = [&](int t, int buf) {
        const int k0 = t * TBK;
#pragma unroll
        for (int q = 0; q < 2; q++) {
            int c = wid * 2 + q;
            int r = c * 16 + lrow;
            int am = min(m0 + r, M - 1);
            int bn = min(r, Kin - 1);
            gll16(A + (size_t)am * K + k0 + lk, &As[buf][c * 512]);
            gll16(B + (size_t)bn * K + k0 + lk, &Bs[buf][c * 512]);
        }
    };

    stage(0, 0);
    __syncthreads();
    for (int t = 0; t < nt; ++t) {
        const int cur = t & 1;
        if (t + 1 < nt) stage(t + 1, cur ^ 1);
        f16x8 af[4], bf[4];
#pragma unroll
        for (int mi = 0; mi < 4; mi++)
            af[mi] = *(const f16x8*)(&As[cur][(wr * 64 + mi * 16 + (lane & 15)) * TBK + (lane >> 4) * 8]);
#pragma unroll
        for (int nj = 0; nj < 4; nj++)
            bf[nj] = *(const f16x8*)(&Bs[cur][(wc * 64 + nj * 16 + (lane & 15)) * TBK + (lane >> 4) * 8]);
#pragma unroll
        for (int mi = 0; mi < 4; mi++)
#pragma unroll
            for (int nj = 0; nj < 4; nj++)
                acc[mi][nj] = __builtin_amdgcn_mfma_f32_16x16x32_f16(af[mi], bf[nj], acc[mi][nj], 0, 0, 0);
        __syncthreads();
    }

    const float denom = fmaxf(1e-6f, sscale[0]);
    const int colbase = wc * 64 + (lane & 15);
    const int g = lane >> 4;
    float cc[4];
#pragma unroll
    for (int nj = 0; nj < 4; nj++) {
        int n = colbase + nj * 16;
        cc[nj] = (n < Kin) ? Csq[n] : 0.f;
    }

    // pass 1: sim values into acc, per-row max -> LDS
#pragma unroll
    for (int mi = 0; mi < 4; mi++) {
#pragma unroll
        for (int r = 0; r < 4; r++) {
            int row = wr * 64 + mi * 16 + g * 4 + r;
            float pp = Psq[m0 + row];
            float mx = -INFINITY;
#pragma unroll
            for (int nj = 0; nj < 4; nj++) {
                int n = colbase + nj * 16;
                float v = -INFINITY;
                if (n < Kin)
                    v = -sqrtf(fmaxf(pp + cc[nj] - 2.f * acc[mi][nj][r], 1e-12f)) / denom;
                acc[mi][nj][r] = v;
                mx = fmaxf(mx, v);
            }
#pragma unroll
            for (int o = 1; o < 16; o <<= 1) mx = fmaxf(mx, __shfl_xor(mx, o));
            if ((lane & 15) == 0) redmx[wc][row] = mx;
        }
    }
    __syncthreads();

    // pass 2: exp + per-row sum -> LDS
#pragma unroll
    for (int mi = 0; mi < 4; mi++) {
#pragma unroll
        for (int r = 0; r < 4; r++) {
            int row = wr * 64 + mi * 16 + g * 4 + r;
            float mx = fmaxf(redmx[0][row], redmx[1][row]);
            float s = 0.f;
#pragma unroll
            for (int nj = 0; nj < 4; nj++) {
                int n = colbase + nj * 16;
                float e = (n < Kin) ? expf(acc[mi][nj][r] - mx) : 0.f;
                acc[mi][nj][r] = e;
                s += e;
            }
#pragma unroll
            for (int o = 1; o < 16; o <<= 1) s += __shfl_xor(s, o);
            if ((lane & 15) == 0) redsm[wc][row] = s;
        }
    }
    __syncthreads();

    // pass 3: normalize + write f16
#pragma unroll
    for (int mi = 0; mi < 4; mi++) {
#pragma unroll
        for (int r = 0; r < 4; r++) {
            int row = wr * 64 + mi * 16 + g * 4 + r;
            float inv = 1.f / (redsm[0][row] + redsm[1][row]);
            int m = m0 + row;
#pragma unroll
            for (int nj = 0; nj < 4; nj++) {
                int n = colbase + nj * 16;
                if (n < Kin)
                    Ah[(size_t)m * Kin + n] = (_Float16)(acc[mi][nj][r] * inv);
            }
        }
    }
}

// ---------------- converters ----------------
__global__ __launch_bounds__(256)
void cvt_k(const float* __restrict__ x, _Float16* __restrict__ y, int n)
{
    int i = (blockIdx.x * 256 + threadIdx.x) * 4;
    if (i < n) {
        float4 v = *(const float4*)(x + i);
        f16x4 h = { (_Float16)v.x, (_Float16)v.y, (_Float16)v.z, (_Float16)v.w };
        *(f16x4*)(y + i) = h;
    }
}

// C [Kin,512] fp32 -> Ch [Kin,512] f16 and CTh [512,Kin] f16
__global__ __launch_bounds__(256)
void cvtC_k(const float* __restrict__ C, _Float16* __restrict__ Ch,
            _Float16* __restrict__ CTh, int Kin)
{
    int i = blockIdx.x * 256 + threadIdx.x;
    if (i < Kin * 512) {
        int j = i >> 9, d = i & 511;
        float v = C[i];
        Ch[i] = (_Float16)v;
        CTh[d * Kin + j] = (_Float16)v;
    }
}

// ---------------- small kernels (f16 activations) ----------------
__global__ __launch_bounds__(256)
void rowsq_k(const _Float16* __restrict__ X, float* __restrict__ out, int M)
{
    int wid = threadIdx.x >> 6, lane = threadIdx.x & 63;
    int row = blockIdx.x * 4 + wid;
    if (row >= M) return;
    f16x8 a = *(const f16x8*)(X + (size_t)row * 512 + lane * 8);
    float s = 0.f;
#pragma unroll
    for (int q = 0; q < 8; q++) { float f = (float)a[q]; s += f * f; }
#pragma unroll
    for (int o = 32; o; o >>= 1) s += __shfl_xor(s, o);
    if (lane == 0) out[row] = s;
}

// Yh = LN(X (+R)) * g + b, f16 in/out, fp32 math; one wave per row
__global__ __launch_bounds__(256)
void ln_k(const _Float16* __restrict__ X, const _Float16* __restrict__ R,
          const float* __restrict__ g, const float* __restrict__ b,
          _Float16* __restrict__ Yh, int M)
{
    int wid = threadIdx.x >> 6, lane = threadIdx.x & 63;
    int row = blockIdx.x * 4 + wid;
    if (row >= M) return;
    f16x8 a = *(const f16x8*)(X + (size_t)row * 512 + lane * 8);
    float v[8];
#pragma unroll
    for (int q = 0; q < 8; q++) v[q] = (float)a[q];
    if (R) {
        f16x8 c = *(const f16x8*)(R + (size_t)row * 512 + lane * 8);
#pragma unroll
        for (int q = 0; q < 8; q++) v[q] += (float)c[q];
    }
    float s = 0.f, ss = 0.f;
#pragma unroll
    for (int q = 0; q < 8; q++) { s += v[q]; ss += v[q] * v[q]; }
#pragma unroll
    for (int o = 32; o; o >>= 1) { s += __shfl_xor(s, o); ss += __shfl_xor(ss, o); }
    float mean = s * (1.f / 512.f);
    float var = ss * (1.f / 512.f) - mean * mean;
    float inv = 1.f / sqrtf(var + 1e-5f);
    int d0 = lane * 8;
    f16x8 o8;
#pragma unroll
    for (int q = 0; q < 8; q++)
        o8[q] = (_Float16)((v[q] - mean) * inv * g[d0 + q] + b[d0 + q]);
    *(f16x8*)(Yh + (size_t)row * 512 + d0) = o8;
}

__global__ __launch_bounds__(256)
void red1_k(const float* __restrict__ C, const float* __restrict__ w1,
            const float* __restrict__ b1, float* __restrict__ H1, int Kin)
{
    int d = blockIdx.x * 256 + threadIdx.x;
    int j = blockIdx.y;
    float acc = b1[j];
    for (int k = 0; k < Kin; k++) acc = fmaf(C[(size_t)k * 512 + d], w1[(size_t)j * Kin + k], acc);
    H1[(size_t)j * 512 + d] = fmaxf(acc, 0.f);
}

__global__ __launch_bounds__(256)
void red2_k(const float* __restrict__ H1, const float* __restrict__ w2,
            const float* __restrict__ b2, float* __restrict__ Cn, int Kin, int Kout)
{
    int d = blockIdx.x * 256 + threadIdx.x;
    int j2 = blockIdx.y;
    float acc = b2[j2];
    for (int j = 0; j < Kin; j++) acc = fmaf(H1[(size_t)j * 512 + d], w2[(size_t)j2 * Kin + j], acc);
    Cn[(size_t)j2 * 512 + d] = acc;
}

// scores[i] = dot(TG[i,:], Ws) + bs; TG f16
__global__ __launch_bounds__(256)
void score_k(const _Float16* __restrict__ TG, const float* __restrict__ Ws,
             const float* __restrict__ bs, float* __restrict__ out, int M)
{
    int wid = threadIdx.x >> 6, lane = threadIdx.x & 63;
    int row = blockIdx.x * 4 + wid;
    if (row >= M) return;
    f16x8 a = *(const f16x8*)(TG + (size_t)row * 512 + lane * 8);
    float4 w0 = *(const float4*)(Ws + lane * 8);
    float4 w1 = *(const float4*)(Ws + lane * 8 + 4);
    float d = (float)a[0] * w0.x + (float)a[1] * w0.y + (float)a[2] * w0.z + (float)a[3] * w0.w
            + (float)a[4] * w1.x + (float)a[5] * w1.y + (float)a[6] * w1.z + (float)a[7] * w1.w;
#pragma unroll
    for (int o = 32; o; o >>= 1) d += __shfl_xor(d, o);
    if (lane == 0) out[row] = d + bs[0];
}

__global__ __launch_bounds__(1024)
void pool_k(float* __restrict__ s, float* __restrict__ scal, int M)
{
    __shared__ float sm[16];
    int tid = threadIdx.x, lane = tid & 63, wid = tid >> 6;
    float mx = -INFINITY;
    for (int i = tid * 4; i < M; i += 4096) {
        float4 a = *(const float4*)(s + i);
        mx = fmaxf(fmaxf(fmaxf(mx, a.x), fmaxf(a.y, a.z)), a.w);
    }
#pragma unroll
    for (int o = 32; o; o >>= 1) mx = fmaxf(mx, __shfl_xor(mx, o));
    if (lane == 0) sm[wid] = mx;
    __syncthreads();
    if (wid == 0) {
        float v = (lane < 16) ? sm[lane] : -INFINITY;
#pragma unroll
        for (int o = 8; o; o >>= 1) v = fmaxf(v, __shfl_xor(v, o));
        if (lane == 0) sm[0] = v;
    }
    __syncthreads();
    float gmax = sm[0];
    __syncthreads();
    float sum = 0.f;
    for (int i = tid * 4; i < M; i += 4096) {
        float4 a = *(const float4*)(s + i);
        float4 e;
        e.x = expf(a.x - gmax); e.y = expf(a.y - gmax);
        e.z = expf(a.z - gmax); e.w = expf(a.w - gmax);
        *(float4*)(s + i) = e;
        sum += e.x + e.y + e.z + e.w;
    }
#pragma unroll
    for (int o = 32; o; o >>= 1) sum += __shfl_xor(sum, o);
    if (lane == 0) sm[wid] = sum;
    __syncthreads();
    if (tid == 0) {
        float t = 0.f;
        for (int w = 0; w < 16; w++) t += sm[w];
        scal[0] = t;
    }
}

__global__ __launch_bounds__(256)
void bagp_k(const _Float16* __restrict__ Z, const float* __restrict__ w,
            float* __restrict__ PB, int M, int cs)
{
    int d = blockIdx.x * 256 + threadIdx.x;
    int chunk = blockIdx.y;
    int i0 = chunk * cs;
    int i1 = min(M, i0 + cs);
    float acc = 0.f;
    for (int i = i0; i < i1; i++) acc = fmaf(w[i], (float)Z[(size_t)i * 512 + d], acc);
    PB[(size_t)chunk * 512 + d] = acc;
}

__global__ __launch_bounds__(256)
void bagf_k(const float* __restrict__ PB, const float* __restrict__ scal,
            float* __restrict__ bag, int nchunk)
{
    int d = blockIdx.x * 256 + threadIdx.x;
    float acc = 0.f;
    for (int c = 0; c < nchunk; c++) acc += PB[(size_t)c * 512 + d];
    bag[d] = acc / scal[0];
}

__global__ __launch_bounds__(256)
void h_k(const float* __restrict__ bag, const float* __restrict__ Wh,
         const float* __restrict__ bh, float* __restrict__ h)
{
    int wid = threadIdx.x >> 6, lane = threadIdx.x & 63;
    int j = blockIdx.x * 4 + wid;
    const float* wr = Wh + (size_t)j * 512;
    float d = 0.f;
#pragma unroll
    for (int t = 0; t < 2; t++) {
        float4 a = *(const float4*)(wr + t * 256 + lane * 4);
        float4 bv = *(const float4*)(bag + t * 256 + lane * 4);
        d += a.x * bv.x + a.y * bv.y + a.z * bv.z + a.w * bv.w;
    }
#pragma unroll
    for (int o = 32; o; o >>= 1) d += __shfl_xor(d, o);
    if (lane == 0) h[j] = fmaxf(d + bh[j], 0.f);
}

__global__ __launch_bounds__(128)
void logit_k(const float* __restrict__ h, const float* __restrict__ Wc,
             const float* __restrict__ bc, float* __restrict__ out)
{
    int wid = threadIdx.x >> 6, lane = threadIdx.x & 63;
    const float* wr = Wc + (size_t)wid * 512;
    float d = 0.f;
#pragma unroll
    for (int t = 0; t < 2; t++) {
        float4 a = *(const float4*)(wr + t * 256 + lane * 4);
        float4 hv = *(const float4*)(h + t * 256 + lane * 4);
        d += a.x * hv.x + a.y * hv.y + a.z * hv.z + a.w * hv.w;
    }
#pragma unroll
    for (int o = 32; o; o >>= 1) d += __shfl_xor(d, o);
    if (lane == 0) out[wid] = d + bc[wid];
}

extern "C" void kernel_launch(void* const* d_in, const int* in_sizes, int n_in,
                              void* d_out, int out_size, void* d_ws, size_t ws_size,
                              hipStream_t stream)
{
    const float* data    = (const float*)d_in[0];
    const float* protos  = (const float*)d_in[1];
    const float* W_pp    = (const float*)d_in[2];
    const float* b_pp    = (const float*)d_in[3];
    const float* W_cp    = (const float*)d_in[4];
    const float* b_cp    = (const float*)d_in[5];
    const float* sscale  = (const float*)d_in[6];
    const float* enh_w1  = (const float*)d_in[7];
    const float* enh_b1  = (const float*)d_in[8];
    const float* enh_w2  = (const float*)d_in[9];
    const float* enh_b2  = (const float*)d_in[10];
    const float* ln_g    = (const float*)d_in[11];
    const float* ln_b    = (const float*)d_in[12];
    const float* red_w1[3] = {(const float*)d_in[13], (const float*)d_in[17], (const float*)d_in[21]};
    const float* red_b1[3] = {(const float*)d_in[14], (const float*)d_in[18], (const float*)d_in[22]};
    const float* red_w2[3] = {(const float*)d_in[15], (const float*)d_in[19], (const float*)d_in[23]};
    const float* red_b2[3] = {(const float*)d_in[16], (const float*)d_in[20], (const float*)d_in[24]};
    const float* W_proc  = (const float*)d_in[25];
    const float* b_proc  = (const float*)d_in[26];
    const float* g_an    = (const float*)d_in[27];
    const float* b_an    = (const float*)d_in[28];
    const float* W_t     = (const float*)d_in[29];
    const float* b_t     = (const float*)d_in[30];
    const float* W_g     = (const float*)d_in[31];
    const float* b_g     = (const float*)d_in[32];
    const float* W_s     = (const float*)d_in[33];
    const float* b_s     = (const float*)d_in[34];
    const float* W_h     = (const float*)d_in[35];
    const float* b_h     = (const float*)d_in[36];
    const float* W_c     = (const float*)d_in[37];
    const float* b_c     = (const float*)d_in[38];
    float* out = (float*)d_out;

    constexpr int N = 32768, DIN = 768, D = 512;
    constexpr int NCHUNK = 256;
    char* w = (char*)d_ws;
    auto alloc = [&](size_t bytes) -> char* {
        char* p = w; w += (bytes + 255) & ~(size_t)255; return p;
    };
    _Float16* Ph     = (_Float16*)alloc((size_t)N * D * 2);
    _Float16* CTXh   = (_Float16*)alloc((size_t)N * D * 2);
    _Float16* TMPh   = (_Float16*)alloc((size_t)N * D * 2);
    _Float16* Zrawh  = (_Float16*)alloc((size_t)(N + 16) * D * 2);
    _Float16* Zh     = (_Float16*)alloc((size_t)(N + 16) * D * 2);
    _Float16* TGh    = (_Float16*)alloc((size_t)(N + 16) * D * 2);
    _Float16* datah  = (_Float16*)alloc((size_t)N * DIN * 2);
    _Float16* Ah     = (_Float16*)alloc((size_t)N * 128 * 2);
    _Float16* Ch     = (_Float16*)alloc(128 * D * 2);
    _Float16* CTh    = (_Float16*)alloc(128 * D * 2);
    _Float16* Wpph   = (_Float16*)alloc((size_t)D * DIN * 2);
    _Float16* w1h    = (_Float16*)alloc((size_t)3 * D * D * 2);
    _Float16* w2h    = (_Float16*)alloc((size_t)3 * D * D * 2);
    _Float16* Wproch = (_Float16*)alloc((size_t)D * D * 2);
    _Float16* Wth    = (_Float16*)alloc((size_t)D * D * 2);
    _Float16* Wgh    = (_Float16*)alloc((size_t)D * D * 2);
    float*    Psq    = (float*)alloc((size_t)N * 4);
    float*    Csq    = (float*)alloc(128 * 4);
    float*    Ca     = (float*)alloc(128 * D * 4);
    float*    Cb     = (float*)alloc(128 * D * 4);
    float*    H1     = (float*)alloc(128 * D * 4);
    float*    scr    = (float*)alloc((size_t)(N + 16) * 4);
    float*    PB     = (float*)alloc((size_t)NCHUNK * D * 4);
    float*    bag    = (float*)alloc(D * 4);
    float*    hb     = (float*)alloc(D * 4);
    float*    scal   = (float*)alloc(8 * 4);

    dim3 blk(256);
    auto cgrid = [](size_t n) { return dim3((unsigned)((n / 4 + 255) / 256)); };
    auto mgrid = [](int M_, int Nout_) { return dim3((Nout_ + TBN - 1) / TBN, (M_ + TBM - 1) / TBM); };

    // --- convert weights + data to f16 ---
    cvt_k<<<cgrid((size_t)N * DIN), blk, 0, stream>>>(data, datah, N * DIN);
    cvt_k<<<cgrid((size_t)D * DIN), blk, 0, stream>>>(W_pp, Wpph, D * DIN);
    cvt_k<<<cgrid((size_t)3 * D * D), blk, 0, stream>>>(enh_w1, w1h, 3 * D * D);
    cvt_k<<<cgrid((size_t)3 * D * D), blk, 0, stream>>>(enh_w2, w2h, 3 * D * D);
    cvt_k<<<cgrid((size_t)D * D), blk, 0, stream>>>(W_proc, Wproch, D * D);
    cvt_k<<<cgrid((size_t)D * D), blk, 0, stream>>>(W_t, Wth, D * D);
    cvt_k<<<cgrid((size_t)D * D), blk, 0, stream>>>(W_g, Wgh, D * D);

    // P = leaky(data @ W_pp^T + b_pp) -> f16
    mgemm<0, 1, false><<<mgrid(N, D), blk, 0, stream>>>(datah, Wpph, b_pp, Ph, nullptr, N, DIN, D);
    // C0 = leaky(protos @ W_cp^T + b_cp) -> fp32 (tiny)
    dot_k<1, false><<<dim3(128 * 512 / 4), blk, 0, stream>>>(protos, W_cp, b_cp, Ca, 128, DIN);

    float* C = Ca;
    float* Cn = Cb;
    int Kin = 128;
    for (int i = 0; i < 3; i++) {
        int Kout = Kin >> 1;
        rowsq_k<<<dim3((N + 3) / 4), blk, 0, stream>>>(Ph, Psq, N);
        cvtC_k<<<dim3((Kin * D + 255) / 256), blk, 0, stream>>>(C, Ch, CTh, Kin);
        rowsq_k<<<dim3((Kin + 3) / 4), blk, 0, stream>>>(Ch, Csq, Kin);
        // A = softmax(-dist/denom) fused with S = P@C^T
        simgemm<<<dim3(1, N / TBM), blk, 0, stream>>>(Ph, Ch, Psq, Csq, sscale, Ah, N, D, Kin);
        // ctx = A @ C -> f16
        mgemm<0, 0, false><<<mgrid(N, D), blk, 0, stream>>>(Ah, CTh, nullptr, CTXh, nullptr, N, Kin, D);
        // P = LN(P + ctx) -> f16
        ln_k<<<dim3((N + 3) / 4), blk, 0, stream>>>(Ph, CTXh, ln_g + (size_t)i * D, ln_b + (size_t)i * D, Ph, N);
        // enhancer MLP: P += w2 @ relu(w1 @ P + b1) + b2
        mgemm<0, 2, false><<<mgrid(N, D), blk, 0, stream>>>(Ph, w1h + (size_t)i * D * D, enh_b1 + (size_t)i * D, TMPh, nullptr, N, D, D);
        mgemm<1, 0, false><<<mgrid(N, D), blk, 0, stream>>>(TMPh, w2h + (size_t)i * D * D, enh_b2 + (size_t)i * D, Ph, nullptr, N, D, D);
        // ProtoReducer (fp32, tiny)
        red1_k<<<dim3(2, Kin), blk, 0, stream>>>(C, red_w1[i], red_b1[i], H1, Kin);
        red2_k<<<dim3(2, Kout), blk, 0, stream>>>(H1, red_w2[i], red_b2[i], Cn, Kin, Kout);
        float* t = C; C = Cn; Cn = t;
        Kin = Kout;
    }

    // Zraw = relu(proc([P; C]))
    mgemm<0, 2, false><<<mgrid(N, D), blk, 0, stream>>>(Ph, Wproch, b_proc, Zrawh, nullptr, N, D, D);
    dot_k<2, true><<<dim3(16 * 512 / 4), blk, 0, stream>>>(C, W_proc, b_proc, Zrawh + (size_t)N * D, 16, D);
    // Z = LN(Zraw)
    ln_k<<<dim3((N + 16 + 3) / 4), blk, 0, stream>>>(Zrawh, nullptr, g_an, b_an, Zh, N + 16);

    // TG = tanh(Z@W_t^T+b_t) * sigmoid(Z@W_g^T+b_g)  (fused dual GEMM)
    gatgemm<<<mgrid(N + 16, D), blk, 0, stream>>>(Zh, Wth, Wgh, b_t, b_g, TGh, N + 16, D, D);

    // attention pooling
    score_k<<<dim3((N + 16 + 3) / 4), blk, 0, stream>>>(TGh, W_s, b_s, scr, N + 16);
    pool_k<<<dim3(1), dim3(1024), 0, stream>>>(scr, scal, N + 16);
    int cs = (N + 16 + NCHUNK - 1) / NCHUNK;
    bagp_k<<<dim3(2, NCHUNK), blk, 0, stream>>>(Zh, scr, PB, N + 16, cs);
    bagf_k<<<dim3(2), blk, 0, stream>>>(PB, scal, bag, NCHUNK);

    // classifier head
    h_k<<<dim3(128), blk, 0, stream>>>(bag, W_h, b_h, hb);
    logit_k<<<dim3(1), dim3(128), 0, stream>>>(hb, W_c, b_c, out);
}